// Round 1
// baseline (426.415 us; speedup 1.0000x reference)
//
#include <hip/hip_runtime.h>

#define L 512
#define D 128
#define H 4
#define HD 32

typedef __bf16 bf16x8 __attribute__((ext_vector_type(8)));
typedef float  f32x4  __attribute__((ext_vector_type(4)));

__device__ __forceinline__ float wave_sum(float v){
#pragma unroll
  for (int o = 32; o; o >>= 1) v += __shfl_xor(v, o);
  return v;
}
__device__ __forceinline__ float wave_max(float v){
#pragma unroll
  for (int o = 32; o; o >>= 1) v = fmaxf(v, __shfl_xor(v, o));
  return v;
}

// ---------------- prep: keep mask + zero padded rows of seqs ----------------
__global__ void k_prep(const int* __restrict__ ls, const float* __restrict__ seqs,
                       float* __restrict__ keep, float* __restrict__ x){
  int tid = blockIdx.x * 256 + threadIdx.x;      // 65536 threads
  int row = tid >> 7;
  float kp = (ls[row] != 0) ? 1.f : 0.f;
  x[tid] = seqs[tid] * kp;
  if ((tid & 127) == 0) keep[row] = kp;
}

// ------------- pre-swizzle Wt (both blocks) into MFMA B-fragment order ------
// b-frag for mfma_f32_16x16x32_bf16: lane holds B[k = quad*8+jj][n = lane&15]
__global__ void k_bfrag(const float* __restrict__ Wt, unsigned short* __restrict__ bf){
  int idx = blockIdx.x * 256 + threadIdx.x;      // 32768 threads
  int jj   = idx & 7;
  int lane = (idx >> 3) & 63;
  int k0   = (idx >> 9) & 3;
  int nt   = idx >> 11;                          // 0..15 (nt<8: block0, nt>=8: block1)
  int d    = k0 * 32 + (lane >> 4) * 8 + jj;
  int col  = (nt & 7) * 16 + (lane & 15);
  int blk  = nt >> 3;
  float v = Wt[blk * D * D + d * D + col];
  __bf16 h = (__bf16)v;
  unsigned short us;
  __builtin_memcpy(&us, &h, 2);
  bf[idx] = us;
}

// ---------------- time-bias: logtw[blk][q][k] = log(sigmoid(...)) -----------
// D = T(262144x128) * [Wt0 | Wt1] (128x256), epilogue relu+dot(Wtp)+logsigmoid
__global__ __launch_bounds__(256, 2) void k_timebias(
    const float* __restrict__ T, const unsigned short* __restrict__ bfg,
    const float* __restrict__ bt, const float* __restrict__ wtp,
    const float* __restrict__ btp, float* __restrict__ logtw){
  __shared__ __align__(16) unsigned short bsh[32768];   // 64 KB: b-fragments
  __shared__ float bts[256], wtps[256];
  int tid = threadIdx.x;
  {
    const uint4* g = (const uint4*)bfg;
    uint4* s = (uint4*)bsh;
#pragma unroll
    for (int i = 0; i < 16; ++i) s[tid + i * 256] = g[tid + i * 256];
    bts[tid]  = bt[tid];     // [2][128] flat
    wtps[tid] = wtp[tid];    // [2][128] flat
  }
  __syncthreads();

  int lane = tid & 63, w = tid >> 6;
  int quad = lane >> 4, m = lane & 15;
  const bf16x8* bls = (const bf16x8*)bsh;
  float bp0 = btp[0], bp1 = btp[1];

  for (int s = 0; s < 2; ++s){
    int strip = blockIdx.x * 2 + s;          // 1024 strips of 256 rows
    int wbase = strip * 256 + w * 64;        // this wave: 64 rows

    // A fragments: 4 m-tiles x 4 k-steps, straight from global, cvt to bf16
    bf16x8 afr[4][4];
#pragma unroll
    for (int mt = 0; mt < 4; ++mt){
      const float* tp = T + (size_t)(wbase + mt * 16 + m) * D + quad * 8;
#pragma unroll
      for (int k0 = 0; k0 < 4; ++k0){
        float4 f0 = *(const float4*)(tp + k0 * 32);
        float4 f1 = *(const float4*)(tp + k0 * 32 + 4);
        bf16x8 a;
        a[0] = (__bf16)f0.x; a[1] = (__bf16)f0.y; a[2] = (__bf16)f0.z; a[3] = (__bf16)f0.w;
        a[4] = (__bf16)f1.x; a[5] = (__bf16)f1.y; a[6] = (__bf16)f1.z; a[7] = (__bf16)f1.w;
        afr[mt][k0] = a;
      }
    }

    float rs[2][4][4] = {};
#pragma unroll
    for (int nt = 0; nt < 16; ++nt){
      f32x4 acc[4] = {{0,0,0,0},{0,0,0,0},{0,0,0,0},{0,0,0,0}};
#pragma unroll
      for (int k0 = 0; k0 < 4; ++k0){
        bf16x8 b = bls[(nt * 4 + k0) * 64 + lane];
#pragma unroll
        for (int mt = 0; mt < 4; ++mt)
          acc[mt] = __builtin_amdgcn_mfma_f32_16x16x32_bf16(afr[mt][k0], b, acc[mt], 0, 0, 0);
      }
      float btv = bts[nt * 16 + m];
      float wtv = wtps[nt * 16 + m];
#pragma unroll
      for (int mt = 0; mt < 4; ++mt)
#pragma unroll
        for (int r = 0; r < 4; ++r){
          float t = fmaxf(acc[mt][r] + btv, 0.f);
          rs[nt >> 3][mt][r] += t * wtv;
        }
    }

    // reduce row-sums across the 16 column-lanes
#pragma unroll
    for (int blk = 0; blk < 2; ++blk)
#pragma unroll
      for (int mt = 0; mt < 4; ++mt)
#pragma unroll
        for (int r = 0; r < 4; ++r){
          float v = rs[blk][mt][r];
          v += __shfl_xor(v, 1); v += __shfl_xor(v, 2);
          v += __shfl_xor(v, 4); v += __shfl_xor(v, 8);
          rs[blk][mt][r] = v;
        }

    if (m == 0){
#pragma unroll
      for (int blk = 0; blk < 2; ++blk){
        float bp = blk ? bp1 : bp0;
        float* out = logtw + blk * (L * L);
#pragma unroll
        for (int mt = 0; mt < 4; ++mt)
#pragma unroll
          for (int r = 0; r < 4; ++r){
            int row = wbase + mt * 16 + quad * 4 + r;
            float sv = rs[blk][mt][r] + bp;
            out[row] = -logf(1.f + expf(-sv));   // log(sigmoid(sv))
          }
      }
    }
  }
}

// ---------------- fused LN1 + Q/K/V projections (+ k transposed) ------------
__global__ __launch_bounds__(128) void k_qkv(
    const float* __restrict__ x, const float* __restrict__ g1, const float* __restrict__ b1,
    const float* __restrict__ Wq, const float* __restrict__ bq,
    const float* __restrict__ Wk, const float* __restrict__ bk,
    const float* __restrict__ Wv, const float* __restrict__ bv,
    float* __restrict__ Q, float* __restrict__ qo,
    float* __restrict__ kT, float* __restrict__ vo){
  __shared__ float xs[128], Qs[128], tmp[2];
  int row = blockIdx.x, c = threadIdx.x;
  float xv = x[row * D + c];
  float s = wave_sum(xv);
  if ((c & 63) == 0) tmp[c >> 6] = s;
  __syncthreads();
  float mean = (tmp[0] + tmp[1]) * (1.f / 128.f);
  __syncthreads();
  float dv = xv - mean;
  float s2 = wave_sum(dv * dv);
  if ((c & 63) == 0) tmp[c >> 6] = s2;
  __syncthreads();
  float var = fmaxf((tmp[0] + tmp[1]) * (1.f / 128.f), 0.f);
  float qn = dv * rsqrtf(var + 1e-8f) * g1[c] + b1[c];
  xs[c] = xv; Qs[c] = qn;
  Q[row * D + c] = qn;
  __syncthreads();
  float aq = 0.f, ak = 0.f, av = 0.f;
#pragma unroll 4
  for (int k = 0; k < 128; ++k){
    float xq = Qs[k], xk = xs[k];
    aq += xq * Wq[k * D + c];
    ak += xk * Wk[k * D + c];
    av += xk * Wv[k * D + c];
  }
  aq += bq[c]; ak += bk[c]; av += bv[c];
  qo[row * D + c] = aq;
  vo[row * D + c] = av;
  kT[(c >> 5) * (HD * L) + (c & 31) * L + row] = ak;   // [H][32][512]
}

// --------- fused scores + time bias + mask + softmax + PV + residual --------
__global__ __launch_bounds__(256) void k_attn(
    const float* __restrict__ q, const float* __restrict__ kT, const float* __restrict__ v,
    const float* __restrict__ logtw, const float* __restrict__ keep,
    const float* __restrict__ Q, float* __restrict__ wout, float* __restrict__ x){
  __shared__ float qv[32];
  __shared__ float sc[512];
  __shared__ float red[4];
  __shared__ float part[8][32];
  int h = blockIdx.x >> 9, qr = blockIdx.x & 511;
  int tid = threadIdx.x;
  if (tid < 32) qv[tid] = q[qr * D + h * HD + tid];
  __syncthreads();
  int j0 = tid, j1 = tid + 256;
  float d0 = 0.f, d1 = 0.f;
  const float* kh = kT + h * (HD * L);
#pragma unroll
  for (int d = 0; d < 32; ++d){
    float qd = qv[d];
    d0 += qd * kh[d * L + j0];
    d1 += qd * kh[d * L + j1];
  }
  const float RS = 0.17677669529663687f;     // 1/sqrt(32)
  float s0 = (d0 + logtw[qr * L + j0]) * RS;
  float s1 = (d1 + logtw[qr * L + j1]) * RS;
  bool padq = (keep[qr] == 0.f);             // block-uniform
  float w0, w1;
  if (padq){
    w0 = 1.f / 512.f; w1 = 1.f / 512.f;      // softmax of all-NEG row: uniform
  } else {
    bool v0ok = (j0 <= qr), v1ok = (j1 <= qr);
    float mx = fmaxf(v0ok ? s0 : -3e38f, v1ok ? s1 : -3e38f);
    { float t = wave_max(mx); if ((tid & 63) == 0) red[tid >> 6] = t; }
    __syncthreads();
    mx = fmaxf(fmaxf(red[0], red[1]), fmaxf(red[2], red[3]));
    __syncthreads();
    float e0 = v0ok ? expf(s0 - mx) : 0.f;
    float e1 = v1ok ? expf(s1 - mx) : 0.f;
    { float t = wave_sum(e0 + e1); if ((tid & 63) == 0) red[tid >> 6] = t; }
    __syncthreads();
    float inv = 1.f / (red[0] + red[1] + red[2] + red[3]);
    w0 = e0 * inv; w1 = e1 * inv;
  }
  sc[j0] = w0; sc[j1] = w1;
  float* wrow = wout + h * (L * L) + qr * L;
  wrow[j0] = w0; wrow[j1] = w1;
  __syncthreads();
  // PV: out[d2] = sum_j w[j] * v[j][h*32+d2], split over 8 thread groups
  int g = tid >> 5, d2 = tid & 31;
  float acc = 0.f;
  const float* vh = v + h * HD + d2;
  for (int j = g * 64; j < g * 64 + 64; ++j) acc += sc[j] * vh[j * D];
  part[g][d2] = acc;
  __syncthreads();
  if (tid < 32){
    float o = part[0][tid] + part[1][tid] + part[2][tid] + part[3][tid]
            + part[4][tid] + part[5][tid] + part[6][tid] + part[7][tid];
    int idx = qr * D + h * HD + tid;
    x[idx] = Q[idx] + o;                     // residual adds post-LN1 Q
  }
}

// ---------------- fused LN2 + FFN (two GEMVs) + residual * keep -------------
__global__ __launch_bounds__(128) void k_ffn(
    const float* __restrict__ xin, const float* __restrict__ g2, const float* __restrict__ b2,
    const float* __restrict__ W1, const float* __restrict__ b1f,
    const float* __restrict__ W2, const float* __restrict__ b2f,
    const float* __restrict__ keep, float* __restrict__ xout){
  __shared__ float x2s[128], y1s[128], tmp[2];
  int row = blockIdx.x, c = threadIdx.x;
  float xv = xin[row * D + c];
  float s = wave_sum(xv);
  if ((c & 63) == 0) tmp[c >> 6] = s;
  __syncthreads();
  float mean = (tmp[0] + tmp[1]) * (1.f / 128.f);
  __syncthreads();
  float dv = xv - mean;
  float s2 = wave_sum(dv * dv);
  if ((c & 63) == 0) tmp[c >> 6] = s2;
  __syncthreads();
  float var = fmaxf((tmp[0] + tmp[1]) * (1.f / 128.f), 0.f);
  float x2 = dv * rsqrtf(var + 1e-8f) * g2[c] + b2[c];
  x2s[c] = x2;
  __syncthreads();
  float a1 = 0.f;
#pragma unroll 4
  for (int k = 0; k < 128; ++k) a1 += x2s[k] * W1[k * D + c];
  a1 = fmaxf(a1 + b1f[c], 0.f);
  y1s[c] = a1;
  __syncthreads();
  float a2 = 0.f;
#pragma unroll 4
  for (int k = 0; k < 128; ++k) a2 += y1s[k] * W2[k * D + c];
  a2 += b2f[c];
  xout[row * D + c] = (x2 + a2) * keep[row]; // FFN residual adds post-LN2 x2
}

// ---------------- final LayerNorm -> d_out[0:65536] -------------------------
__global__ __launch_bounds__(128) void k_lnf(
    const float* __restrict__ x, const float* __restrict__ g, const float* __restrict__ b,
    float* __restrict__ out){
  __shared__ float tmp[2];
  int row = blockIdx.x, c = threadIdx.x;
  float xv = x[row * D + c];
  float s = wave_sum(xv);
  if ((c & 63) == 0) tmp[c >> 6] = s;
  __syncthreads();
  float mean = (tmp[0] + tmp[1]) * (1.f / 128.f);
  __syncthreads();
  float dv = xv - mean;
  float s2 = wave_sum(dv * dv);
  if ((c & 63) == 0) tmp[c >> 6] = s2;
  __syncthreads();
  float var = fmaxf((tmp[0] + tmp[1]) * (1.f / 128.f), 0.f);
  out[row * D + c] = dv * rsqrtf(var + 1e-8f) * g[c] + b[c];
}

extern "C" void kernel_launch(void* const* d_in, const int* in_sizes, int n_in,
                              void* d_out, int out_size, void* d_ws, size_t ws_size,
                              hipStream_t stream){
  const int*   ls   = (const int*)d_in[0];
  const float* seqs = (const float*)d_in[1];
  const float* T    = (const float*)d_in[2];
  const float* Wq   = (const float*)d_in[3];
  const float* bq   = (const float*)d_in[4];
  const float* Wk   = (const float*)d_in[5];
  const float* bk   = (const float*)d_in[6];
  const float* Wv   = (const float*)d_in[7];
  const float* bv   = (const float*)d_in[8];
  const float* Wt   = (const float*)d_in[9];
  const float* bt   = (const float*)d_in[10];
  const float* Wtp  = (const float*)d_in[11];
  const float* btp  = (const float*)d_in[12];
  const float* g1   = (const float*)d_in[13];
  const float* b1   = (const float*)d_in[14];
  const float* g2   = (const float*)d_in[15];
  const float* b2   = (const float*)d_in[16];
  const float* W1   = (const float*)d_in[17];
  const float* b1f  = (const float*)d_in[18];
  const float* W2   = (const float*)d_in[19];
  const float* b2f  = (const float*)d_in[20];
  const float* lg   = (const float*)d_in[21];
  const float* lb   = (const float*)d_in[22];

  float* ws   = (float*)d_ws;
  float* keep = ws;                 // 512
  float* x    = ws + 512;           // 65536
  float* Q    = x + 65536;          // 65536
  float* qb   = Q + 65536;          // 65536
  float* vb   = qb + 65536;         // 65536
  float* kT   = vb + 65536;         // 65536
  float* logtw= kT + 65536;         // 2*262144
  unsigned short* bfg = (unsigned short*)(logtw + 2 * 262144);  // 32768 ushort

  float* outF = (float*)d_out;
  float* lf = outF;                 // 65536 log_feats
  float* w0 = outF + 65536;         // 4*512*512 attn block 0
  float* w1 = w0 + 1048576;         // 4*512*512 attn block 1

  k_prep   <<<256, 256, 0, stream>>>(ls, seqs, keep, x);
  k_bfrag  <<<128, 256, 0, stream>>>(Wt, bfg);
  k_timebias<<<512, 256, 0, stream>>>(T, bfg, bt, Wtp, btp, logtw);

  for (int blk = 0; blk < 2; ++blk){
    int o = blk * D * D, ob = blk * D;
    k_qkv <<<512, 128, 0, stream>>>(x, g1 + ob, b1 + ob, Wq + o, bq + ob,
                                    Wk + o, bk + ob, Wv + o, bv + ob,
                                    Q, qb, kT, vb);
    k_attn<<<2048, 256, 0, stream>>>(qb, kT, vb, logtw + blk * (L * L), keep,
                                     Q, blk ? w1 : w0, x);
    k_ffn <<<512, 128, 0, stream>>>(x, g2 + ob, b2 + ob, W1 + o, b1f + ob,
                                    W2 + o, b2f + ob, keep, x);
  }
  k_lnf<<<512, 128, 0, stream>>>(x, lg, lb, lf);
}

// Round 2
// 327.328 us; speedup vs baseline: 1.3027x; 1.3027x over previous
//
#include <hip/hip_runtime.h>

#define L 512
#define D 128
#define H 4
#define HD 32

typedef __bf16 bf16x8 __attribute__((ext_vector_type(8)));
typedef float  f32x4  __attribute__((ext_vector_type(4)));

__device__ __forceinline__ float wave_sum(float v){
#pragma unroll
  for (int o = 32; o; o >>= 1) v += __shfl_xor(v, o);
  return v;
}
__device__ __forceinline__ float wave_max(float v){
#pragma unroll
  for (int o = 32; o; o >>= 1) v = fmaxf(v, __shfl_xor(v, o));
  return v;
}

// ------------- pre-swizzle Wt (both blocks) into MFMA B-fragment order ------
// b-frag for mfma_f32_16x16x32_bf16: lane holds B[k = quad*8+jj][n = lane&15]
__global__ void k_bfrag(const float* __restrict__ Wt, unsigned short* __restrict__ bf){
  int idx = blockIdx.x * 256 + threadIdx.x;      // 32768 threads
  int jj   = idx & 7;
  int lane = (idx >> 3) & 63;
  int k0   = (idx >> 9) & 3;
  int nt   = idx >> 11;                          // 0..15 (nt<8: block0, nt>=8: block1)
  int d    = k0 * 32 + (lane >> 4) * 8 + jj;
  int col  = (nt & 7) * 16 + (lane & 15);
  int blk  = nt >> 3;
  float v = Wt[blk * D * D + d * D + col];
  __bf16 h = (__bf16)v;
  unsigned short us;
  __builtin_memcpy(&us, &h, 2);
  bf[idx] = us;
}

// ---------------- time-bias: logtw[blk][q][k] = log(sigmoid(...)) -----------
// D = T(262144x128) * [Wt0 | Wt1] (128x256), epilogue relu+dot(Wtp)+logsigmoid
// Register-pressure-aware: rs[4][4] reused per weight-block; no strip loop.
__global__ __launch_bounds__(256, 2) void k_timebias(
    const float* __restrict__ T, const unsigned short* __restrict__ bfg,
    const float* __restrict__ bt, const float* __restrict__ wtp,
    const float* __restrict__ btp, float* __restrict__ logtw){
  __shared__ __align__(16) unsigned short bsh[32768];   // 64 KB: b-fragments
  __shared__ float bts[256], wtps[256];
  int tid = threadIdx.x;
  {
    const uint4* g = (const uint4*)bfg;
    uint4* s = (uint4*)bsh;
#pragma unroll
    for (int i = 0; i < 16; ++i) s[tid + i * 256] = g[tid + i * 256];
    bts[tid]  = bt[tid];     // [2][128] flat
    wtps[tid] = wtp[tid];    // [2][128] flat
  }
  __syncthreads();

  int lane = tid & 63, w = tid >> 6;
  int quad = lane >> 4, m = lane & 15;
  const bf16x8* bls = (const bf16x8*)bsh;
  int wbase = blockIdx.x * 256 + w * 64;     // this wave: 64 rows of T

  // A fragments: 4 m-tiles x 4 k-steps, straight from global, cvt to bf16
  bf16x8 afr[4][4];
#pragma unroll
  for (int mt = 0; mt < 4; ++mt){
    const float* tp = T + (size_t)(wbase + mt * 16 + m) * D + quad * 8;
#pragma unroll
    for (int k0 = 0; k0 < 4; ++k0){
      float4 f0 = *(const float4*)(tp + k0 * 32);
      float4 f1 = *(const float4*)(tp + k0 * 32 + 4);
      bf16x8 a;
      a[0] = (__bf16)f0.x; a[1] = (__bf16)f0.y; a[2] = (__bf16)f0.z; a[3] = (__bf16)f0.w;
      a[4] = (__bf16)f1.x; a[5] = (__bf16)f1.y; a[6] = (__bf16)f1.z; a[7] = (__bf16)f1.w;
      afr[mt][k0] = a;
    }
  }

#pragma unroll
  for (int blk = 0; blk < 2; ++blk){
    f32x4 rs[4] = {{0,0,0,0},{0,0,0,0},{0,0,0,0},{0,0,0,0}};
#pragma unroll
    for (int ntl = 0; ntl < 8; ++ntl){
      int nt = blk * 8 + ntl;
      f32x4 acc[4] = {{0,0,0,0},{0,0,0,0},{0,0,0,0},{0,0,0,0}};
#pragma unroll
      for (int k0 = 0; k0 < 4; ++k0){
        bf16x8 b = bls[(nt * 4 + k0) * 64 + lane];
#pragma unroll
        for (int mt = 0; mt < 4; ++mt)
          acc[mt] = __builtin_amdgcn_mfma_f32_16x16x32_bf16(afr[mt][k0], b, acc[mt], 0, 0, 0);
      }
      float btv = bts[nt * 16 + m];
      float wtv = wtps[nt * 16 + m];
#pragma unroll
      for (int mt = 0; mt < 4; ++mt)
#pragma unroll
        for (int r = 0; r < 4; ++r)
          rs[mt][r] += fmaxf(acc[mt][r] + btv, 0.f) * wtv;
    }
    // reduce row-sums across the 16 column-lanes
#pragma unroll
    for (int mt = 0; mt < 4; ++mt)
#pragma unroll
      for (int r = 0; r < 4; ++r){
        float v = rs[mt][r];
        v += __shfl_xor(v, 1); v += __shfl_xor(v, 2);
        v += __shfl_xor(v, 4); v += __shfl_xor(v, 8);
        rs[mt][r] = v;
      }
    if (m == 0){
      float bp = btp[blk];
      float* out = logtw + blk * (L * L);
#pragma unroll
      for (int mt = 0; mt < 4; ++mt){
        float4 o;
        float s0 = rs[mt][0] + bp; o.x = -logf(1.f + expf(-s0));
        float s1 = rs[mt][1] + bp; o.y = -logf(1.f + expf(-s1));
        float s2 = rs[mt][2] + bp; o.z = -logf(1.f + expf(-s2));
        float s3 = rs[mt][3] + bp; o.w = -logf(1.f + expf(-s3));
        *(float4*)(out + wbase + mt * 16 + quad * 4) = o;
      }
    }
  }
}

// ---------------- fused (mask) + LN1 + Q/K/V projections (+ k transposed) ---
__global__ __launch_bounds__(128) void k_qkv(
    const float* __restrict__ src, const int* __restrict__ ls, int domask,
    const float* __restrict__ g1, const float* __restrict__ b1,
    const float* __restrict__ Wq, const float* __restrict__ bq,
    const float* __restrict__ Wk, const float* __restrict__ bk,
    const float* __restrict__ Wv, const float* __restrict__ bv,
    float* __restrict__ Q, float* __restrict__ qo,
    float* __restrict__ kT, float* __restrict__ vo){
  __shared__ float xs[128], Qs[128], tmp[2];
  int row = blockIdx.x, c = threadIdx.x;
  float xv = src[row * D + c];
  if (domask && ls[row] == 0) xv = 0.f;
  float s = wave_sum(xv);
  if ((c & 63) == 0) tmp[c >> 6] = s;
  __syncthreads();
  float mean = (tmp[0] + tmp[1]) * (1.f / 128.f);
  __syncthreads();
  float dv = xv - mean;
  float s2 = wave_sum(dv * dv);
  if ((c & 63) == 0) tmp[c >> 6] = s2;
  __syncthreads();
  float var = fmaxf((tmp[0] + tmp[1]) * (1.f / 128.f), 0.f);
  float qn = dv * rsqrtf(var + 1e-8f) * g1[c] + b1[c];
  xs[c] = xv; Qs[c] = qn;
  Q[row * D + c] = qn;
  __syncthreads();
  float aq = 0.f, ak = 0.f, av = 0.f;
#pragma unroll 4
  for (int k = 0; k < 128; ++k){
    float xq = Qs[k], xk = xs[k];
    aq += xq * Wq[k * D + c];
    ak += xk * Wk[k * D + c];
    av += xk * Wv[k * D + c];
  }
  aq += bq[c]; ak += bk[c]; av += bv[c];
  qo[row * D + c] = aq;
  vo[row * D + c] = av;
  kT[(c >> 5) * (HD * L) + (c & 31) * L + row] = ak;   // [H][32][512]
}

// ------ fused attention (all 4 heads, one block per query row) + FFN --------
// block = 256 threads = 4 waves; wave h handles head h. Then LN2+FFN on the
// completed row; for the last block also the final LayerNorm.
__global__ __launch_bounds__(256) void k_attn_ffn(
    const float* __restrict__ qb, const float* __restrict__ kT, const float* __restrict__ vb,
    const float* __restrict__ logtw, const int* __restrict__ ls,
    const float* __restrict__ Q,
    const float* __restrict__ g2, const float* __restrict__ b2,
    const float* __restrict__ W1, const float* __restrict__ b1f,
    const float* __restrict__ W2, const float* __restrict__ b2f,
    const float* __restrict__ lg, const float* __restrict__ lb,
    float* __restrict__ wout, float* __restrict__ xout,
    float* __restrict__ lf, int last){
  __shared__ float qsh[128];
  __shared__ float sc[4][512];
  __shared__ float xr[128];
  __shared__ float x2s[128];
  __shared__ float y1s[128];
  __shared__ float pstore[256];
  __shared__ float st[2];
  int qr = blockIdx.x;
  int tid = threadIdx.x;
  int lane = tid & 63, h = tid >> 6;

  if (tid < 128) qsh[tid] = qb[qr * D + tid];
  __syncthreads();

  // ---- phase 1: scores + softmax (wave-local, head h) ----
  const float* kh = kT + h * (HD * L);
  const float* ltw = logtw + qr * L;
  const float RS = 0.17677669529663687f;     // 1/sqrt(32)
  float s[8];
#pragma unroll
  for (int jj = 0; jj < 8; ++jj){
    int j = jj * 64 + lane;
    float d = 0.f;
#pragma unroll
    for (int dd = 0; dd < 32; ++dd) d += qsh[h * HD + dd] * kh[dd * L + j];
    s[jj] = (d + ltw[j]) * RS;
  }
  bool padq = (ls[qr] == 0);
  float wgt[8];
  if (padq){
#pragma unroll
    for (int jj = 0; jj < 8; ++jj) wgt[jj] = 1.f / 512.f;  // all-NEG row: uniform
  } else {
    float mx = -3e38f;
#pragma unroll
    for (int jj = 0; jj < 8; ++jj){ int j = jj * 64 + lane; if (j <= qr) mx = fmaxf(mx, s[jj]); }
    mx = wave_max(mx);
    float sum = 0.f;
#pragma unroll
    for (int jj = 0; jj < 8; ++jj){
      int j = jj * 64 + lane;
      float e = (j <= qr) ? expf(s[jj] - mx) : 0.f;
      wgt[jj] = e; sum += e;
    }
    sum = wave_sum(sum);
    float inv = 1.f / sum;
#pragma unroll
    for (int jj = 0; jj < 8; ++jj) wgt[jj] *= inv;
  }
  float* wrow = wout + h * (L * L) + qr * L;
#pragma unroll
  for (int jj = 0; jj < 8; ++jj){
    int j = jj * 64 + lane;
    sc[h][j] = wgt[jj];
    wrow[j] = wgt[jj];
  }
  __syncthreads();

  // ---- phase 2: PV + residual (adds post-LN1 Q) ----
  int g = lane >> 5, d2 = lane & 31;
  const float* vh = vb + h * HD + d2;
  const float* sch = sc[h];
  float acc = 0.f;
  for (int j = g * 256; j < g * 256 + 256; ++j) acc += sch[j] * vh[(size_t)j * D];
  acc += __shfl_xor(acc, 32);
  if (g == 0){
    int idx = qr * D + h * HD + d2;
    xr[h * HD + d2] = Q[idx] + acc;
  }
  __syncthreads();

  // ---- phase 3: LN2 ----
  if (tid < 64){
    float a = xr[tid], b = xr[tid + 64];
    float s1 = wave_sum(a + b);
    float s2 = wave_sum(a * a + b * b);
    if (tid == 0){
      float mean = s1 * (1.f / 128.f);
      float var = fmaxf(s2 * (1.f / 128.f) - mean * mean, 0.f);
      st[0] = mean; st[1] = rsqrtf(var + 1e-8f);
    }
  }
  __syncthreads();
  int c = tid & 127, half = tid >> 7;
  if (half == 0) x2s[c] = (xr[c] - st[0]) * st[1] * g2[c] + b2[c];
  __syncthreads();

  // ---- FFN1 (k-split over 2 halves) ----
  float a1 = 0.f;
  {
    int k0 = half * 64;
#pragma unroll 8
    for (int k = 0; k < 64; ++k) a1 += x2s[k0 + k] * W1[(k0 + k) * D + c];
  }
  pstore[tid] = a1;
  __syncthreads();
  if (half == 0) y1s[c] = fmaxf(pstore[c] + pstore[c + 128] + b1f[c], 0.f);
  __syncthreads();

  // ---- FFN2 (k-split) ----
  float a2 = 0.f;
  {
    int k0 = half * 64;
#pragma unroll 8
    for (int k = 0; k < 64; ++k) a2 += y1s[k0 + k] * W2[(k0 + k) * D + c];
  }
  pstore[tid] = a2;
  __syncthreads();
  float kp = (ls[qr] != 0) ? 1.f : 0.f;
  if (half == 0){
    float xo = (x2s[c] + pstore[c] + pstore[c + 128] + b2f[c]) * kp;  // residual adds post-LN2 x2
    xr[c] = xo;
    if (!last) xout[qr * D + c] = xo;
  }
  __syncthreads();

  // ---- final LayerNorm (last block only) ----
  if (last){
    if (tid < 64){
      float a = xr[tid], b = xr[tid + 64];
      float s1 = wave_sum(a + b);
      float s2 = wave_sum(a * a + b * b);
      if (tid == 0){
        float mean = s1 * (1.f / 128.f);
        float var = fmaxf(s2 * (1.f / 128.f) - mean * mean, 0.f);
        st[0] = mean; st[1] = rsqrtf(var + 1e-8f);
      }
    }
    __syncthreads();
    if (half == 0) lf[qr * D + c] = (xr[c] - st[0]) * st[1] * lg[c] + lb[c];
  }
}

extern "C" void kernel_launch(void* const* d_in, const int* in_sizes, int n_in,
                              void* d_out, int out_size, void* d_ws, size_t ws_size,
                              hipStream_t stream){
  const int*   ls   = (const int*)d_in[0];
  const float* seqs = (const float*)d_in[1];
  const float* T    = (const float*)d_in[2];
  const float* Wq   = (const float*)d_in[3];
  const float* bq   = (const float*)d_in[4];
  const float* Wk   = (const float*)d_in[5];
  const float* bk   = (const float*)d_in[6];
  const float* Wv   = (const float*)d_in[7];
  const float* bv   = (const float*)d_in[8];
  const float* Wt   = (const float*)d_in[9];
  const float* bt   = (const float*)d_in[10];
  const float* Wtp  = (const float*)d_in[11];
  const float* btp  = (const float*)d_in[12];
  const float* g1   = (const float*)d_in[13];
  const float* b1   = (const float*)d_in[14];
  const float* g2   = (const float*)d_in[15];
  const float* b2   = (const float*)d_in[16];
  const float* W1   = (const float*)d_in[17];
  const float* b1f  = (const float*)d_in[18];
  const float* W2   = (const float*)d_in[19];
  const float* b2f  = (const float*)d_in[20];
  const float* lg   = (const float*)d_in[21];
  const float* lb   = (const float*)d_in[22];

  float* ws   = (float*)d_ws;
  float* x    = ws;                 // 65536 residual stream
  float* Q    = x + 65536;          // 65536
  float* qb   = Q + 65536;          // 65536
  float* vb   = qb + 65536;         // 65536
  float* kT   = vb + 65536;         // 65536
  float* logtw= kT + 65536;         // 2*262144
  unsigned short* bfg = (unsigned short*)(logtw + 2 * 262144);  // 32768 ushort

  float* outF = (float*)d_out;
  float* lf = outF;                 // 65536 log_feats
  float* w0 = outF + 65536;         // 4*512*512 attn block 0
  float* w1 = w0 + 1048576;         // 4*512*512 attn block 1

  k_bfrag   <<<128, 256, 0, stream>>>(Wt, bfg);
  k_timebias<<<1024, 256, 0, stream>>>(T, bfg, bt, Wtp, btp, logtw);

  for (int blk = 0; blk < 2; ++blk){
    int o = blk * D * D, ob = blk * D;
    const float* src = blk ? x : seqs;
    k_qkv <<<512, 128, 0, stream>>>(src, ls, blk == 0 ? 1 : 0,
                                    g1 + ob, b1 + ob, Wq + o, bq + ob,
                                    Wk + o, bk + ob, Wv + o, bv + ob,
                                    Q, qb, kT, vb);
    k_attn_ffn<<<512, 256, 0, stream>>>(qb, kT, vb, logtw + blk * (L * L), ls,
                                        Q, g2 + ob, b2 + ob, W1 + o, b1f + ob,
                                        W2 + o, b2f + ob, lg, lb,
                                        blk ? w1 : w0, x, lf, blk);
  }
}

// Round 3
// 320.961 us; speedup vs baseline: 1.3286x; 1.0198x over previous
//
#include <hip/hip_runtime.h>

#define L 512
#define D 128
#define H 4
#define HD 32

typedef __bf16 bf16x8 __attribute__((ext_vector_type(8)));
typedef float  f32x4  __attribute__((ext_vector_type(4)));

__device__ __forceinline__ float wave_sum(float v){
#pragma unroll
  for (int o = 32; o; o >>= 1) v += __shfl_xor(v, o);
  return v;
}
__device__ __forceinline__ unsigned short bfbits(float v){
  __bf16 h = (__bf16)v;
  unsigned short u;
  __builtin_memcpy(&u, &h, 2);
  return u;
}

// ------------- pre-swizzle Wt (both blocks) into MFMA B-fragment order ------
__global__ void k_bfrag(const float* __restrict__ Wt, unsigned short* __restrict__ bf){
  int idx = blockIdx.x * 256 + threadIdx.x;      // 32768 threads
  int jj   = idx & 7;
  int lane = (idx >> 3) & 63;
  int k0   = (idx >> 9) & 3;
  int nt   = idx >> 11;
  int d    = k0 * 32 + (lane >> 4) * 8 + jj;
  int col  = (nt & 7) * 16 + (lane & 15);
  int blk  = nt >> 3;
  bf[idx] = bfbits(Wt[blk * D * D + d * D + col]);
}

// ---------------- time-bias: logtw[blk][q][k] = log(sigmoid(...)) -----------
__global__ __launch_bounds__(256, 2) void k_timebias(
    const float* __restrict__ T, const unsigned short* __restrict__ bfg,
    const float* __restrict__ bt, const float* __restrict__ wtp,
    const float* __restrict__ btp, float* __restrict__ logtw){
  __shared__ __align__(16) unsigned short bsh[32768];
  __shared__ float bts[256], wtps[256];
  int tid = threadIdx.x;
  {
    const uint4* g = (const uint4*)bfg;
    uint4* s = (uint4*)bsh;
#pragma unroll
    for (int i = 0; i < 16; ++i) s[tid + i * 256] = g[tid + i * 256];
    bts[tid]  = bt[tid];
    wtps[tid] = wtp[tid];
  }
  __syncthreads();

  int lane = tid & 63, w = tid >> 6;
  int quad = lane >> 4, m = lane & 15;
  const bf16x8* bls = (const bf16x8*)bsh;
  int wbase = blockIdx.x * 256 + w * 64;

  bf16x8 afr[4][4];
#pragma unroll
  for (int mt = 0; mt < 4; ++mt){
    const float* tp = T + (size_t)(wbase + mt * 16 + m) * D + quad * 8;
#pragma unroll
    for (int k0 = 0; k0 < 4; ++k0){
      float4 f0 = *(const float4*)(tp + k0 * 32);
      float4 f1 = *(const float4*)(tp + k0 * 32 + 4);
      bf16x8 a;
      a[0] = (__bf16)f0.x; a[1] = (__bf16)f0.y; a[2] = (__bf16)f0.z; a[3] = (__bf16)f0.w;
      a[4] = (__bf16)f1.x; a[5] = (__bf16)f1.y; a[6] = (__bf16)f1.z; a[7] = (__bf16)f1.w;
      afr[mt][k0] = a;
    }
  }

#pragma unroll
  for (int blk = 0; blk < 2; ++blk){
    f32x4 rs[4] = {{0,0,0,0},{0,0,0,0},{0,0,0,0},{0,0,0,0}};
#pragma unroll
    for (int ntl = 0; ntl < 8; ++ntl){
      int nt = blk * 8 + ntl;
      f32x4 acc[4] = {{0,0,0,0},{0,0,0,0},{0,0,0,0},{0,0,0,0}};
#pragma unroll
      for (int k0 = 0; k0 < 4; ++k0){
        bf16x8 b = bls[(nt * 4 + k0) * 64 + lane];
#pragma unroll
        for (int mt = 0; mt < 4; ++mt)
          acc[mt] = __builtin_amdgcn_mfma_f32_16x16x32_bf16(afr[mt][k0], b, acc[mt], 0, 0, 0);
      }
      float btv = bts[nt * 16 + m];
      float wtv = wtps[nt * 16 + m];
#pragma unroll
      for (int mt = 0; mt < 4; ++mt)
#pragma unroll
        for (int r = 0; r < 4; ++r)
          rs[mt][r] += fmaxf(acc[mt][r] + btv, 0.f) * wtv;
    }
#pragma unroll
    for (int mt = 0; mt < 4; ++mt)
#pragma unroll
      for (int r = 0; r < 4; ++r){
        float v = rs[mt][r];
        v += __shfl_xor(v, 1); v += __shfl_xor(v, 2);
        v += __shfl_xor(v, 4); v += __shfl_xor(v, 8);
        rs[mt][r] = v;
      }
    if (m == 0){
      float bp = btp[blk];
      float* out = logtw + blk * (L * L);
#pragma unroll
      for (int mt = 0; mt < 4; ++mt){
        float4 o;
        float s0 = rs[mt][0] + bp; o.x = -logf(1.f + expf(-s0));
        float s1 = rs[mt][1] + bp; o.y = -logf(1.f + expf(-s1));
        float s2 = rs[mt][2] + bp; o.z = -logf(1.f + expf(-s2));
        float s3 = rs[mt][3] + bp; o.w = -logf(1.f + expf(-s3));
        *(float4*)(out + wbase + mt * 16 + quad * 4) = o;
      }
    }
  }
}

// -------- fragment-write helpers (thread owns value at (row, c)) ------------
// qA: A-frag of q per (qtile, head): elem A[m=lane&15][k=quad*8+j], k=c&31
__device__ __forceinline__ void write_qA(unsigned short* qA, int row, int c, float v){
  int qt = row >> 4, m = row & 15;
  int h = c >> 5, cc = c & 31;
  qA[(((qt * 4 + h) * 64) + (cc >> 3) * 16 + m) * 8 + (cc & 7)] = bfbits(v);
}
// kB: B-frag (scores): B[k=head-dim (c&31)][n=row]; 32 n-tiles per head
__device__ __forceinline__ void write_kB(unsigned short* kB, int row, int c, float v){
  int h = c >> 5, cc = c & 31;
  int nt = row >> 4;
  kB[((h * 32 + nt) * 64 + (cc >> 3) * 16 + (row & 15)) * 8 + (cc & 7)] = bfbits(v);
}
// vB: B-frag (PV): B[k=row (512, 16 steps)][n=c&31 (2 tiles)]
__device__ __forceinline__ void write_vB(unsigned short* vB, int row, int c, float v){
  int h = c >> 5, cc = c & 31;
  int kk = row >> 5, qv = (row >> 3) & 3, jv = row & 7;
  int nt = cc >> 4;
  vB[(((h * 16 + kk) * 2 + nt) * 64 + qv * 16 + (cc & 15)) * 8 + jv] = bfbits(v);
}

// ---------------- block0: mask + LN1 + QKV (fragments out) ------------------
__global__ __launch_bounds__(128) void k_qkv0(
    const float* __restrict__ src, const int* __restrict__ ls,
    const float* __restrict__ g1, const float* __restrict__ b1,
    const float* __restrict__ Wq, const float* __restrict__ bq,
    const float* __restrict__ Wk, const float* __restrict__ bk,
    const float* __restrict__ Wv, const float* __restrict__ bv,
    float* __restrict__ Q, unsigned short* __restrict__ qA,
    unsigned short* __restrict__ kB, unsigned short* __restrict__ vB){
  __shared__ float xs[128], Qs[128], tmp[2];
  int row = blockIdx.x, c = threadIdx.x;
  float xv = src[row * D + c];
  if (ls[row] == 0) xv = 0.f;
  float s = wave_sum(xv);
  if ((c & 63) == 0) tmp[c >> 6] = s;
  __syncthreads();
  float mean = (tmp[0] + tmp[1]) * (1.f / 128.f);
  __syncthreads();
  float dv = xv - mean;
  float s2 = wave_sum(dv * dv);
  if ((c & 63) == 0) tmp[c >> 6] = s2;
  __syncthreads();
  float var = fmaxf((tmp[0] + tmp[1]) * (1.f / 128.f), 0.f);
  float qn = dv * rsqrtf(var + 1e-8f) * g1[c] + b1[c];
  xs[c] = xv; Qs[c] = qn;
  Q[row * D + c] = qn;
  __syncthreads();
  float aq = 0.f, ak = 0.f, av = 0.f;
#pragma unroll 4
  for (int k = 0; k < 128; ++k){
    float xq = Qs[k], xk = xs[k];
    aq += xq * Wq[k * D + c];
    ak += xk * Wk[k * D + c];
    av += xk * Wv[k * D + c];
  }
  write_qA(qA, row, c, aq + bq[c]);
  write_kB(kB, row, c, ak + bk[c]);
  write_vB(vB, row, c, av + bv[c]);
}

// ---------------- MFMA attention: block = (qtile of 16 rows, head) ----------
__global__ __launch_bounds__(256) void k_attn(
    const unsigned short* __restrict__ qA, const unsigned short* __restrict__ kB,
    const unsigned short* __restrict__ vB, const float* __restrict__ logtw,
    const int* __restrict__ ls, const float* __restrict__ Q,
    float* __restrict__ wout, float* __restrict__ xr){
  __shared__ __align__(16) unsigned short pa[16 * 64 * 8];  // P in A-frag order (16 KB)
  __shared__ float pvp[4][2][64][4];                        // PV partials (8 KB)
  __shared__ float smax[4][16], ssum[4][16];
  int qt = blockIdx.x >> 2, h = blockIdx.x & 3;
  int tid = threadIdx.x, lane = tid & 63, w = tid >> 6;
  int quad = lane >> 4, mcol = lane & 15;
  const float RS = 0.17677669529663687f;   // 1/sqrt(32)

  bf16x8 qf = ((const bf16x8*)qA)[(qt * 4 + h) * 64 + lane];

  // ---- scores: 8 n-tiles (cols w*128 .. w*128+127) ----
  f32x4 acc[8];
#pragma unroll
  for (int nt8 = 0; nt8 < 8; ++nt8){
    bf16x8 bf = ((const bf16x8*)kB)[(h * 32 + w * 8 + nt8) * 64 + lane];
    f32x4 z = {0, 0, 0, 0};
    acc[nt8] = __builtin_amdgcn_mfma_f32_16x16x32_bf16(qf, bf, z, 0, 0, 0);
  }

  float e[8][4];
  float mx4[4] = {-3e38f, -3e38f, -3e38f, -3e38f};
#pragma unroll
  for (int nt8 = 0; nt8 < 8; ++nt8){
    int col = w * 128 + nt8 * 16 + mcol;
#pragma unroll
    for (int r = 0; r < 4; ++r){
      int row = qt * 16 + quad * 4 + r;
      float sv = (acc[nt8][r] + logtw[row * L + col]) * RS;
      sv = (col <= row) ? sv : -3e38f;
      e[nt8][r] = sv;
      mx4[r] = fmaxf(mx4[r], sv);
    }
  }
#pragma unroll
  for (int r = 0; r < 4; ++r){
    float v = mx4[r];
    v = fmaxf(v, __shfl_xor(v, 1)); v = fmaxf(v, __shfl_xor(v, 2));
    v = fmaxf(v, __shfl_xor(v, 4)); v = fmaxf(v, __shfl_xor(v, 8));
    mx4[r] = v;
  }
  if (mcol == 0){
#pragma unroll
    for (int r = 0; r < 4; ++r) smax[w][quad * 4 + r] = mx4[r];
  }
  __syncthreads();
  float mxr[4], sum4[4] = {0, 0, 0, 0};
#pragma unroll
  for (int r = 0; r < 4; ++r){
    int rr = quad * 4 + r;
    mxr[r] = fmaxf(fmaxf(smax[0][rr], smax[1][rr]), fmaxf(smax[2][rr], smax[3][rr]));
  }
#pragma unroll
  for (int nt8 = 0; nt8 < 8; ++nt8)
#pragma unroll
    for (int r = 0; r < 4; ++r){
      float sv = e[nt8][r];
      float ev = (sv > -1e38f) ? expf(sv - mxr[r]) : 0.f;
      e[nt8][r] = ev;
      sum4[r] += ev;
    }
#pragma unroll
  for (int r = 0; r < 4; ++r){
    float v = sum4[r];
    v += __shfl_xor(v, 1); v += __shfl_xor(v, 2);
    v += __shfl_xor(v, 4); v += __shfl_xor(v, 8);
    sum4[r] = v;
  }
  if (mcol == 0){
#pragma unroll
    for (int r = 0; r < 4; ++r) ssum[w][quad * 4 + r] = sum4[r];
  }
  __syncthreads();
  float inv[4]; int padr[4];
#pragma unroll
  for (int r = 0; r < 4; ++r){
    int rr = quad * 4 + r;
    inv[r] = 1.f / (ssum[0][rr] + ssum[1][rr] + ssum[2][rr] + ssum[3][rr]);
    padr[r] = (ls[qt * 16 + rr] == 0);
  }
  // ---- normalize, write wout, stash P into LDS (A-frag order) ----
#pragma unroll
  for (int nt8 = 0; nt8 < 8; ++nt8){
    int col = w * 128 + nt8 * 16 + mcol;
    int kk = col >> 5, qk = (col >> 3) & 3, jj = col & 7;
#pragma unroll
    for (int r = 0; r < 4; ++r){
      int rl = quad * 4 + r;
      float wv = padr[r] ? (1.f / 512.f) : e[nt8][r] * inv[r];
      wout[h * (L * L) + (qt * 16 + rl) * L + col] = wv;
      pa[(kk * 64 + qk * 16 + rl) * 8 + jj] = bfbits(wv);
    }
  }

  // ---- PV: wave w handles k-range [w*128, w*128+128) (its own pa writes) ----
  f32x4 pacc[2] = {{0,0,0,0},{0,0,0,0}};
#pragma unroll
  for (int kk4 = 0; kk4 < 4; ++kk4){
    int kk = w * 4 + kk4;
    bf16x8 af = ((const bf16x8*)pa)[kk * 64 + lane];
#pragma unroll
    for (int nt = 0; nt < 2; ++nt){
      bf16x8 bf = ((const bf16x8*)vB)[((h * 16 + kk) * 2 + nt) * 64 + lane];
      pacc[nt] = __builtin_amdgcn_mfma_f32_16x16x32_bf16(af, bf, pacc[nt], 0, 0, 0);
    }
  }
#pragma unroll
  for (int nt = 0; nt < 2; ++nt)
#pragma unroll
    for (int r = 0; r < 4; ++r) pvp[w][nt][lane][r] = pacc[nt][r];
  __syncthreads();
  if (w < 2){
    int nt = w;
#pragma unroll
    for (int r = 0; r < 4; ++r){
      float o = pvp[0][nt][lane][r] + pvp[1][nt][lane][r]
              + pvp[2][nt][lane][r] + pvp[3][nt][lane][r];
      int row = qt * 16 + quad * 4 + r;
      int cg = h * HD + nt * 16 + mcol;
      xr[row * D + cg] = Q[row * D + cg] + o;   // residual adds post-LN1 Q
    }
  }
}

// ------- LN2 + FFN + keep; optionally fuse next block's LN1+QKV or final LN --
__global__ __launch_bounds__(256) void k_ffn(
    const float* __restrict__ xr, const int* __restrict__ ls,
    const float* __restrict__ g2, const float* __restrict__ b2,
    const float* __restrict__ W1, const float* __restrict__ b1f,
    const float* __restrict__ W2, const float* __restrict__ b2f,
    int fuse_qkv,
    const float* __restrict__ g1, const float* __restrict__ b1,
    const float* __restrict__ Wq, const float* __restrict__ bq,
    const float* __restrict__ Wk, const float* __restrict__ bk,
    const float* __restrict__ Wv, const float* __restrict__ bv,
    float* __restrict__ Q, unsigned short* __restrict__ qA,
    unsigned short* __restrict__ kB, unsigned short* __restrict__ vB,
    int fuse_lnf, const float* __restrict__ lg, const float* __restrict__ lb,
    float* __restrict__ lf){
  __shared__ float xrs[128], x2s[128], y1s[128], pstore[256], st[2];
  int row = blockIdx.x, tid = threadIdx.x;
  int c = tid & 127, half = tid >> 7;
  if (half == 0) xrs[c] = xr[row * D + c];
  __syncthreads();
  if (tid < 64){
    float a = xrs[tid], b = xrs[tid + 64];
    float s1 = wave_sum(a + b);
    float s2 = wave_sum(a * a + b * b);
    if (tid == 0){
      float mean = s1 * (1.f / 128.f);
      float var = fmaxf(s2 * (1.f / 128.f) - mean * mean, 0.f);
      st[0] = mean; st[1] = rsqrtf(var + 1e-8f);
    }
  }
  __syncthreads();
  if (half == 0) x2s[c] = (xrs[c] - st[0]) * st[1] * g2[c] + b2[c];
  __syncthreads();
  float a1 = 0.f;
  { int k0 = half * 64;
#pragma unroll 8
    for (int k = 0; k < 64; ++k) a1 += x2s[k0 + k] * W1[(k0 + k) * D + c]; }
  pstore[tid] = a1;
  __syncthreads();
  if (half == 0) y1s[c] = fmaxf(pstore[c] + pstore[c + 128] + b1f[c], 0.f);
  __syncthreads();
  float a2 = 0.f;
  { int k0 = half * 64;
#pragma unroll 8
    for (int k = 0; k < 64; ++k) a2 += y1s[k0 + k] * W2[(k0 + k) * D + c]; }
  pstore[tid] = a2;
  __syncthreads();
  float kp = (ls[row] != 0) ? 1.f : 0.f;
  if (half == 0)
    xrs[c] = (x2s[c] + pstore[c] + pstore[c + 128] + b2f[c]) * kp;  // adds post-LN2 x2
  __syncthreads();

  if (fuse_qkv){
    // LN1 of next block on xo (= xrs)
    if (tid < 64){
      float a = xrs[tid], b = xrs[tid + 64];
      float s1 = wave_sum(a + b);
      float s2 = wave_sum(a * a + b * b);
      if (tid == 0){
        float mean = s1 * (1.f / 128.f);
        float var = fmaxf(s2 * (1.f / 128.f) - mean * mean, 0.f);
        st[0] = mean; st[1] = rsqrtf(var + 1e-8f);
      }
    }
    __syncthreads();
    if (half == 0){
      float qn = (xrs[c] - st[0]) * st[1] * g1[c] + b1[c];
      y1s[c] = qn;                       // reuse as Qs
      Q[row * D + c] = qn;
    }
    __syncthreads();
    float avp = 0.f;
    if (half == 0){
      float aq = 0.f;
#pragma unroll 4
      for (int k = 0; k < 128; ++k) aq += y1s[k] * Wq[k * D + c];
#pragma unroll 8
      for (int k = 0; k < 64; ++k) avp += xrs[k] * Wv[k * D + c];
      write_qA(qA, row, c, aq + bq[c]);
    } else {
      float ak = 0.f;
#pragma unroll 4
      for (int k = 0; k < 128; ++k) ak += xrs[k] * Wk[k * D + c];
#pragma unroll 8
      for (int k = 64; k < 128; ++k) avp += xrs[k] * Wv[k * D + c];
      write_kB(kB, row, c, ak + bk[c]);
    }
    pstore[tid] = avp;
    __syncthreads();
    if (half == 1)
      write_vB(vB, row, c, pstore[c] + pstore[c + 128] + bv[c]);
  }

  if (fuse_lnf){
    if (tid < 64){
      float a = xrs[tid], b = xrs[tid + 64];
      float s1 = wave_sum(a + b);
      float s2 = wave_sum(a * a + b * b);
      if (tid == 0){
        float mean = s1 * (1.f / 128.f);
        float var = fmaxf(s2 * (1.f / 128.f) - mean * mean, 0.f);
        st[0] = mean; st[1] = rsqrtf(var + 1e-8f);
      }
    }
    __syncthreads();
    if (half == 0) lf[row * D + c] = (xrs[c] - st[0]) * st[1] * lg[c] + lb[c];
  }
}

extern "C" void kernel_launch(void* const* d_in, const int* in_sizes, int n_in,
                              void* d_out, int out_size, void* d_ws, size_t ws_size,
                              hipStream_t stream){
  const int*   ls   = (const int*)d_in[0];
  const float* seqs = (const float*)d_in[1];
  const float* T    = (const float*)d_in[2];
  const float* Wq   = (const float*)d_in[3];
  const float* bq   = (const float*)d_in[4];
  const float* Wk   = (const float*)d_in[5];
  const float* bk   = (const float*)d_in[6];
  const float* Wv   = (const float*)d_in[7];
  const float* bv   = (const float*)d_in[8];
  const float* Wt   = (const float*)d_in[9];
  const float* bt   = (const float*)d_in[10];
  const float* Wtp  = (const float*)d_in[11];
  const float* btp  = (const float*)d_in[12];
  const float* g1   = (const float*)d_in[13];
  const float* b1   = (const float*)d_in[14];
  const float* g2   = (const float*)d_in[15];
  const float* b2   = (const float*)d_in[16];
  const float* W1   = (const float*)d_in[17];
  const float* b1f  = (const float*)d_in[18];
  const float* W2   = (const float*)d_in[19];
  const float* b2f  = (const float*)d_in[20];
  const float* lg   = (const float*)d_in[21];
  const float* lb   = (const float*)d_in[22];

  float* ws    = (float*)d_ws;
  float* Q     = ws;                  // 65536
  float* xr    = Q + 65536;           // 65536
  float* logtw = xr + 65536;          // 2*262144
  unsigned short* bfg = (unsigned short*)(logtw + 2 * 262144);  // 32768
  unsigned short* qA  = bfg + 32768;  // 65536
  unsigned short* kB  = qA + 65536;   // 65536
  unsigned short* vB  = kB + 65536;   // 65536

  float* outF = (float*)d_out;
  float* lf = outF;
  float* w0 = outF + 65536;
  float* w1 = w0 + 1048576;

  k_bfrag   <<<128, 256, 0, stream>>>(Wt, bfg);
  k_timebias<<<1024, 256, 0, stream>>>(T, bfg, bt, Wtp, btp, logtw);

  // block 0
  k_qkv0<<<512, 128, 0, stream>>>(seqs, ls, g1, b1, Wq, bq, Wk, bk, Wv, bv,
                                  Q, qA, kB, vB);
  k_attn<<<128, 256, 0, stream>>>(qA, kB, vB, logtw, ls, Q, w0, xr);
  // FFN(block0) fused with LN1+QKV(block1)
  k_ffn<<<512, 256, 0, stream>>>(xr, ls, g2, b2, W1, b1f, W2, b2f,
                                 1, g1 + D, b1 + D, Wq + D * D, bq + D,
                                 Wk + D * D, bk + D, Wv + D * D, bv + D,
                                 Q, qA, kB, vB,
                                 0, lg, lb, lf);
  // block 1
  k_attn<<<128, 256, 0, stream>>>(qA, kB, vB, logtw + L * L, ls, Q, w1, xr);
  k_ffn<<<512, 256, 0, stream>>>(xr, ls, g2 + D, b2 + D, W1 + D * D, b1f + D,
                                 W2 + D * D, b2f + D,
                                 0, g1, b1, Wq, bq, Wk, bk, Wv, bv,
                                 Q, qA, kB, vB,
                                 1, lg, lb, lf);
}

// Round 4
// 299.114 us; speedup vs baseline: 1.4256x; 1.0730x over previous
//
#include <hip/hip_runtime.h>

#define L 512
#define D 128
#define H 4
#define HD 32
#define XLD 132   // padded LDS leading dim (floats) to break 16-way bank conflicts

typedef __bf16 bf16x8 __attribute__((ext_vector_type(8)));
typedef float  f32x4  __attribute__((ext_vector_type(4)));

__device__ __forceinline__ unsigned short bfbits(float v){
  __bf16 h = (__bf16)v; unsigned short u; __builtin_memcpy(&u, &h, 2); return u;
}
__device__ __forceinline__ bf16x8 cvt8(float4 a0, float4 a1){
  bf16x8 r;
  r[0] = (__bf16)a0.x; r[1] = (__bf16)a0.y; r[2] = (__bf16)a0.z; r[3] = (__bf16)a0.w;
  r[4] = (__bf16)a1.x; r[5] = (__bf16)a1.y; r[6] = (__bf16)a1.z; r[7] = (__bf16)a1.w;
  return r;
}

// -------- fragment-write helpers (thread owns value at (row, c)) ------------
__device__ __forceinline__ void write_qA(unsigned short* qA, int row, int c, float v){
  int qt = row >> 4, m = row & 15;
  int h = c >> 5, cc = c & 31;
  qA[(((qt * 4 + h) * 64) + (cc >> 3) * 16 + m) * 8 + (cc & 7)] = bfbits(v);
}
__device__ __forceinline__ void write_kB(unsigned short* kB, int row, int c, float v){
  int h = c >> 5, cc = c & 31;
  int nt = row >> 4;
  kB[((h * 32 + nt) * 64 + (cc >> 3) * 16 + (row & 15)) * 8 + (cc & 7)] = bfbits(v);
}
__device__ __forceinline__ void write_vB(unsigned short* vB, int row, int c, float v){
  int h = c >> 5, cc = c & 31;
  int kk = row >> 5, qv = (row >> 3) & 3, jv = row & 7;
  int nt = cc >> 4;
  vB[(((h * 16 + kk) * 2 + nt) * 64 + qv * 16 + (cc & 15)) * 8 + jv] = bfbits(v);
}

// ---- per-16-row stats (block of 256 threads; thread t: row=t>>4, seg=t&15) --
__device__ __forceinline__ void row_stats16(const float (*buf)[XLD], int tid,
                                            float* mean_s, float* rstd_s){
  int row_l = tid >> 4, seg = tid & 15;
  const float* p = &buf[row_l][seg * 8];
  float4 f0 = *(const float4*)p, f1 = *(const float4*)(p + 4);
  float sum = f0.x + f0.y + f0.z + f0.w + f1.x + f1.y + f1.z + f1.w;
  float sq  = f0.x*f0.x + f0.y*f0.y + f0.z*f0.z + f0.w*f0.w
            + f1.x*f1.x + f1.y*f1.y + f1.z*f1.z + f1.w*f1.w;
#pragma unroll
  for (int o = 1; o < 16; o <<= 1){ sum += __shfl_xor(sum, o); sq += __shfl_xor(sq, o); }
  if (seg == 0){
    float mn = sum * (1.f / 128.f);
    mean_s[row_l] = mn;
    rstd_s[row_l] = rsqrtf(fmaxf(sq * (1.f / 128.f) - mn * mn, 0.f) + 1e-8f);
  }
}

// ---- A-fragment builders from a 16x128 LDS tile ----------------------------
__device__ __forceinline__ void build_afr(const float (*buf)[XLD], int lane, bf16x8* afr){
  int m = lane & 15, quad = lane >> 4;
#pragma unroll
  for (int k0 = 0; k0 < 4; ++k0){
    const float* p = &buf[m][k0 * 32 + quad * 8];
    afr[k0] = cvt8(*(const float4*)p, *(const float4*)(p + 4));
  }
}
__device__ __forceinline__ void build_afr_ln(const float (*buf)[XLD], int lane,
    const float* mean_s, const float* rstd_s,
    const float* __restrict__ g, const float* __restrict__ b, bf16x8* afr){
  int m = lane & 15, quad = lane >> 4;
  float mn = mean_s[m], rs = rstd_s[m];
#pragma unroll
  for (int k0 = 0; k0 < 4; ++k0){
    int c0 = k0 * 32 + quad * 8;
    const float* p = &buf[m][c0];
    float4 a0 = *(const float4*)p, a1 = *(const float4*)(p + 4);
    float q[8];
    q[0]=(a0.x-mn)*rs*g[c0+0]+b[c0+0]; q[1]=(a0.y-mn)*rs*g[c0+1]+b[c0+1];
    q[2]=(a0.z-mn)*rs*g[c0+2]+b[c0+2]; q[3]=(a0.w-mn)*rs*g[c0+3]+b[c0+3];
    q[4]=(a1.x-mn)*rs*g[c0+4]+b[c0+4]; q[5]=(a1.y-mn)*rs*g[c0+5]+b[c0+5];
    q[6]=(a1.z-mn)*rs*g[c0+6]+b[c0+6]; q[7]=(a1.w-mn)*rs*g[c0+7]+b[c0+7];
    bf16x8 r;
    r[0]=(__bf16)q[0]; r[1]=(__bf16)q[1]; r[2]=(__bf16)q[2]; r[3]=(__bf16)q[3];
    r[4]=(__bf16)q[4]; r[5]=(__bf16)q[5]; r[6]=(__bf16)q[6]; r[7]=(__bf16)q[7];
    afr[k0] = r;
  }
}

// ------------- prep: swizzle Wt (timebias layout) + 10 GEMM weights ---------
// wf layout (bf16x8 units): [((mat*8 + nt)*4 + k0)*64 + lane], mat = blk*5 + {q,k,v,W1,W2}
__global__ void k_prep(const float* __restrict__ Wt,
                       const float* __restrict__ Wq, const float* __restrict__ Wk,
                       const float* __restrict__ Wv, const float* __restrict__ W1,
                       const float* __restrict__ W2,
                       unsigned short* __restrict__ bfg, unsigned short* __restrict__ wf){
  int idx = blockIdx.x * 256 + threadIdx.x;      // 196608 threads
  if (idx < 32768){
    int jj   = idx & 7;
    int lane = (idx >> 3) & 63;
    int k0   = (idx >> 9) & 3;
    int nt   = idx >> 11;
    int d    = k0 * 32 + (lane >> 4) * 8 + jj;
    int col  = (nt & 7) * 16 + (lane & 15);
    int blk  = nt >> 3;
    bfg[idx] = bfbits(Wt[blk * D * D + d * D + col]);
  } else {
    int i2 = idx - 32768;
    int jj = i2 & 7, lane = (i2 >> 3) & 63, k0 = (i2 >> 9) & 3, nt = (i2 >> 11) & 7;
    int mat = i2 >> 14;                          // 0..9
    int blk = mat / 5, m5 = mat % 5;
    const float* W = (m5 == 0 ? Wq : m5 == 1 ? Wk : m5 == 2 ? Wv : m5 == 3 ? W1 : W2)
                     + blk * D * D;
    int d = k0 * 32 + (lane >> 4) * 8 + jj;
    int col = nt * 16 + (lane & 15);
    wf[i2] = bfbits(W[d * D + col]);
  }
}

// ---------------- time-bias: logtw[blk][q][k] = log(sigmoid(...)) -----------
// 32 KB LDS per pass (one weight-block at a time) -> 4 blocks/CU occupancy.
__global__ __launch_bounds__(256, 4) void k_timebias(
    const float* __restrict__ T, const unsigned short* __restrict__ bfg,
    const float* __restrict__ bt, const float* __restrict__ wtp,
    const float* __restrict__ btp, float* __restrict__ logtw){
  __shared__ __align__(16) unsigned short bsh[16384];   // 32 KB
  __shared__ float bts[128], wtps[128];
  int tid = threadIdx.x;
  int lane = tid & 63, w = tid >> 6;
  int quad = lane >> 4, m = lane & 15;
  const bf16x8* bls = (const bf16x8*)bsh;
  int wbase = blockIdx.x * 256 + w * 64;

  bf16x8 afr[4][4];
#pragma unroll
  for (int mt = 0; mt < 4; ++mt){
    const float* tp = T + (size_t)(wbase + mt * 16 + m) * D + quad * 8;
#pragma unroll
    for (int k0 = 0; k0 < 4; ++k0){
      float4 f0 = *(const float4*)(tp + k0 * 32);
      float4 f1 = *(const float4*)(tp + k0 * 32 + 4);
      afr[mt][k0] = cvt8(f0, f1);
    }
  }

#pragma unroll
  for (int blk = 0; blk < 2; ++blk){
    if (blk) __syncthreads();                   // protect bsh overwrite
    {
      const uint4* g = (const uint4*)(bfg + blk * 16384);
      uint4* s = (uint4*)bsh;
#pragma unroll
      for (int i = 0; i < 8; ++i) s[tid + i * 256] = g[tid + i * 256];
      if (tid < 128){ bts[tid] = bt[blk * 128 + tid]; wtps[tid] = wtp[blk * 128 + tid]; }
    }
    __syncthreads();

    f32x4 rs[4] = {{0,0,0,0},{0,0,0,0},{0,0,0,0},{0,0,0,0}};
#pragma unroll
    for (int ntl = 0; ntl < 8; ++ntl){
      f32x4 acc[4] = {{0,0,0,0},{0,0,0,0},{0,0,0,0},{0,0,0,0}};
#pragma unroll
      for (int k0 = 0; k0 < 4; ++k0){
        bf16x8 b = bls[(ntl * 4 + k0) * 64 + lane];
#pragma unroll
        for (int mt = 0; mt < 4; ++mt)
          acc[mt] = __builtin_amdgcn_mfma_f32_16x16x32_bf16(afr[mt][k0], b, acc[mt], 0, 0, 0);
      }
      float btv = bts[ntl * 16 + m];
      float wtv = wtps[ntl * 16 + m];
#pragma unroll
      for (int mt = 0; mt < 4; ++mt)
#pragma unroll
        for (int r = 0; r < 4; ++r)
          rs[mt][r] += fmaxf(acc[mt][r] + btv, 0.f) * wtv;
    }
#pragma unroll
    for (int mt = 0; mt < 4; ++mt)
#pragma unroll
      for (int r = 0; r < 4; ++r){
        float v = rs[mt][r];
        v += __shfl_xor(v, 1); v += __shfl_xor(v, 2);
        v += __shfl_xor(v, 4); v += __shfl_xor(v, 8);
        rs[mt][r] = v;
      }
    if (m == 0){
      float bp = btp[blk];
      float* out = logtw + blk * (L * L);
#pragma unroll
      for (int mt = 0; mt < 4; ++mt){
        float4 o;
        float s0 = rs[mt][0] + bp; o.x = -logf(1.f + expf(-s0));
        float s1 = rs[mt][1] + bp; o.y = -logf(1.f + expf(-s1));
        float s2 = rs[mt][2] + bp; o.z = -logf(1.f + expf(-s2));
        float s3 = rs[mt][3] + bp; o.w = -logf(1.f + expf(-s3));
        *(float4*)(out + wbase + mt * 16 + quad * 4) = o;
      }
    }
  }
}

// -------------- MFMA LN1+QKV: block = 16 rows, 4 waves split 24 ntile-jobs --
__global__ __launch_bounds__(256) void k_qkv_m(
    const float* __restrict__ src, const int* __restrict__ ls, int domask,
    const float* __restrict__ g1, const float* __restrict__ b1,
    const unsigned short* __restrict__ wf, int matq,
    const float* __restrict__ bq, const float* __restrict__ bk,
    const float* __restrict__ bv,
    float* __restrict__ Q, unsigned short* __restrict__ qA,
    unsigned short* __restrict__ kB, unsigned short* __restrict__ vB){
  __shared__ float xs[16][XLD];
  __shared__ float mean_s[16], rstd_s[16];
  __shared__ float g1s[128], b1s[128];
  int tid = threadIdx.x, rowbase = blockIdx.x * 16;
  int row_l = tid >> 4, seg = tid & 15;

  const float* sp = src + (rowbase + row_l) * D + seg * 8;
  float4 f0 = *(const float4*)sp, f1 = *(const float4*)(sp + 4);
  if (domask && ls[rowbase + row_l] == 0){
    f0 = make_float4(0,0,0,0); f1 = make_float4(0,0,0,0);
  }
  *(float4*)&xs[row_l][seg * 8] = f0;
  *(float4*)&xs[row_l][seg * 8 + 4] = f1;
  if (tid < 128){ g1s[tid] = g1[tid]; b1s[tid] = b1[tid]; }
  __syncthreads();
  row_stats16(xs, tid, mean_s, rstd_s);
  __syncthreads();

  // write Q (post-LN1, fp32) for the attention residual
  {
    float mn = mean_s[row_l], rs = rstd_s[row_l];
    float* qp = Q + (rowbase + row_l) * D + seg * 8;
    float4 o0, o1;
    int c0 = seg * 8;
    o0.x=(f0.x-mn)*rs*g1s[c0+0]+b1s[c0+0]; o0.y=(f0.y-mn)*rs*g1s[c0+1]+b1s[c0+1];
    o0.z=(f0.z-mn)*rs*g1s[c0+2]+b1s[c0+2]; o0.w=(f0.w-mn)*rs*g1s[c0+3]+b1s[c0+3];
    o1.x=(f1.x-mn)*rs*g1s[c0+4]+b1s[c0+4]; o1.y=(f1.y-mn)*rs*g1s[c0+5]+b1s[c0+5];
    o1.z=(f1.z-mn)*rs*g1s[c0+6]+b1s[c0+6]; o1.w=(f1.w-mn)*rs*g1s[c0+7]+b1s[c0+7];
    *(float4*)qp = o0; *(float4*)(qp + 4) = o1;
  }

  int lane = tid & 63, w = tid >> 6;
  int quad = lane >> 4, mcol = lane & 15;
  bf16x8 afrQ[4], afrX[4];
  build_afr_ln(xs, lane, mean_s, rstd_s, g1s, b1s, afrQ);
  build_afr(xs, lane, afrX);

#pragma unroll
  for (int jl = 0; jl < 6; ++jl){
    int j = w * 6 + jl;
    int mat = j >> 3, nt = j & 7;
    const bf16x8* wfb = (const bf16x8*)wf + ((size_t)(matq + mat) * 8 + nt) * 4 * 64;
    f32x4 acc = {0, 0, 0, 0};
#pragma unroll
    for (int k0 = 0; k0 < 4; ++k0)
      acc = __builtin_amdgcn_mfma_f32_16x16x32_bf16(mat == 0 ? afrQ[k0] : afrX[k0],
                                                    wfb[k0 * 64 + lane], acc, 0, 0, 0);
    int c = nt * 16 + mcol;
    float bias = (mat == 0 ? bq : mat == 1 ? bk : bv)[c];
#pragma unroll
    for (int r = 0; r < 4; ++r){
      int row = rowbase + quad * 4 + r;
      float v = acc[r] + bias;
      if (mat == 0) write_qA(qA, row, c, v);
      else if (mat == 1) write_kB(kB, row, c, v);
      else write_vB(vB, row, c, v);
    }
  }
}

// ---------------- MFMA attention: block = (qtile of 16 rows, head) ----------
__global__ __launch_bounds__(256) void k_attn(
    const unsigned short* __restrict__ qA, const unsigned short* __restrict__ kB,
    const unsigned short* __restrict__ vB, const float* __restrict__ logtw,
    const int* __restrict__ ls, const float* __restrict__ Q,
    float* __restrict__ wout, float* __restrict__ xr){
  __shared__ __align__(16) unsigned short pa[16 * 64 * 8];
  __shared__ float pvp[4][2][64][4];
  __shared__ float smax[4][16], ssum[4][16];
  int qt = blockIdx.x >> 2, h = blockIdx.x & 3;
  int tid = threadIdx.x, lane = tid & 63, w = tid >> 6;
  int quad = lane >> 4, mcol = lane & 15;
  const float RS = 0.17677669529663687f;

  bf16x8 qf = ((const bf16x8*)qA)[(qt * 4 + h) * 64 + lane];

  f32x4 acc[8];
#pragma unroll
  for (int nt8 = 0; nt8 < 8; ++nt8){
    bf16x8 bf = ((const bf16x8*)kB)[(h * 32 + w * 8 + nt8) * 64 + lane];
    f32x4 z = {0, 0, 0, 0};
    acc[nt8] = __builtin_amdgcn_mfma_f32_16x16x32_bf16(qf, bf, z, 0, 0, 0);
  }

  float e[8][4];
  float mx4[4] = {-3e38f, -3e38f, -3e38f, -3e38f};
#pragma unroll
  for (int nt8 = 0; nt8 < 8; ++nt8){
    int col = w * 128 + nt8 * 16 + mcol;
#pragma unroll
    for (int r = 0; r < 4; ++r){
      int row = qt * 16 + quad * 4 + r;
      float sv = (acc[nt8][r] + logtw[row * L + col]) * RS;
      sv = (col <= row) ? sv : -3e38f;
      e[nt8][r] = sv;
      mx4[r] = fmaxf(mx4[r], sv);
    }
  }
#pragma unroll
  for (int r = 0; r < 4; ++r){
    float v = mx4[r];
    v = fmaxf(v, __shfl_xor(v, 1)); v = fmaxf(v, __shfl_xor(v, 2));
    v = fmaxf(v, __shfl_xor(v, 4)); v = fmaxf(v, __shfl_xor(v, 8));
    mx4[r] = v;
  }
  if (mcol == 0){
#pragma unroll
    for (int r = 0; r < 4; ++r) smax[w][quad * 4 + r] = mx4[r];
  }
  __syncthreads();
  float mxr[4], sum4[4] = {0, 0, 0, 0};
#pragma unroll
  for (int r = 0; r < 4; ++r){
    int rr = quad * 4 + r;
    mxr[r] = fmaxf(fmaxf(smax[0][rr], smax[1][rr]), fmaxf(smax[2][rr], smax[3][rr]));
  }
#pragma unroll
  for (int nt8 = 0; nt8 < 8; ++nt8)
#pragma unroll
    for (int r = 0; r < 4; ++r){
      float sv = e[nt8][r];
      float ev = (sv > -1e38f) ? expf(sv - mxr[r]) : 0.f;
      e[nt8][r] = ev;
      sum4[r] += ev;
    }
#pragma unroll
  for (int r = 0; r < 4; ++r){
    float v = sum4[r];
    v += __shfl_xor(v, 1); v += __shfl_xor(v, 2);
    v += __shfl_xor(v, 4); v += __shfl_xor(v, 8);
    sum4[r] = v;
  }
  if (mcol == 0){
#pragma unroll
    for (int r = 0; r < 4; ++r) ssum[w][quad * 4 + r] = sum4[r];
  }
  __syncthreads();
  float inv[4]; int padr[4];
#pragma unroll
  for (int r = 0; r < 4; ++r){
    int rr = quad * 4 + r;
    inv[r] = 1.f / (ssum[0][rr] + ssum[1][rr] + ssum[2][rr] + ssum[3][rr]);
    padr[r] = (ls[qt * 16 + rr] == 0);
  }
#pragma unroll
  for (int nt8 = 0; nt8 < 8; ++nt8){
    int col = w * 128 + nt8 * 16 + mcol;
    int kk = col >> 5, qk = (col >> 3) & 3, jj = col & 7;
#pragma unroll
    for (int r = 0; r < 4; ++r){
      int rl = quad * 4 + r;
      float wv = padr[r] ? (1.f / 512.f) : e[nt8][r] * inv[r];
      wout[h * (L * L) + (qt * 16 + rl) * L + col] = wv;
      pa[(kk * 64 + qk * 16 + rl) * 8 + jj] = bfbits(wv);
    }
  }

  f32x4 pacc[2] = {{0,0,0,0},{0,0,0,0}};
#pragma unroll
  for (int kk4 = 0; kk4 < 4; ++kk4){
    int kk = w * 4 + kk4;
    bf16x8 af = ((const bf16x8*)pa)[kk * 64 + lane];
#pragma unroll
    for (int nt = 0; nt < 2; ++nt){
      bf16x8 bf = ((const bf16x8*)vB)[((h * 16 + kk) * 2 + nt) * 64 + lane];
      pacc[nt] = __builtin_amdgcn_mfma_f32_16x16x32_bf16(af, bf, pacc[nt], 0, 0, 0);
    }
  }
#pragma unroll
  for (int nt = 0; nt < 2; ++nt)
#pragma unroll
    for (int r = 0; r < 4; ++r) pvp[w][nt][lane][r] = pacc[nt][r];
  __syncthreads();
  if (w < 2){
    int nt = w;
#pragma unroll
    for (int r = 0; r < 4; ++r){
      float o = pvp[0][nt][lane][r] + pvp[1][nt][lane][r]
              + pvp[2][nt][lane][r] + pvp[3][nt][lane][r];
      int row = qt * 16 + quad * 4 + r;
      int cg = h * HD + nt * 16 + mcol;
      xr[row * D + cg] = Q[row * D + cg] + o;
    }
  }
}

// ---- MFMA LN2+FFN (+keep); optional fused LN1+QKV of next block / final LN --
__global__ __launch_bounds__(256) void k_ffn_m(
    const float* __restrict__ xr, const int* __restrict__ ls,
    const float* __restrict__ g2, const float* __restrict__ b2,
    const unsigned short* __restrict__ wf, int mat1,
    const float* __restrict__ b1f, const float* __restrict__ b2f,
    int fuse_qkv, const float* __restrict__ g1, const float* __restrict__ b1,
    int matq, const float* __restrict__ bq, const float* __restrict__ bk,
    const float* __restrict__ bv,
    float* __restrict__ Q, unsigned short* __restrict__ qA,
    unsigned short* __restrict__ kB, unsigned short* __restrict__ vB,
    int fuse_lnf, const float* __restrict__ lg, const float* __restrict__ lb,
    float* __restrict__ lf){
  __shared__ float xs[16][XLD];
  __shared__ float x2s[16][XLD];
  __shared__ float y1s[16][XLD];
  __shared__ float xos[16][XLD];
  __shared__ float mean_s[16], rstd_s[16];
  __shared__ float gs[128], bs[128];
  int tid = threadIdx.x, rowbase = blockIdx.x * 16;
  int row_l = tid >> 4, seg = tid & 15;
  int lane = tid & 63, w = tid >> 6;
  int quad = lane >> 4, mcol = lane & 15;

  {
    const float* sp = xr + (rowbase + row_l) * D + seg * 8;
    *(float4*)&xs[row_l][seg * 8] = *(const float4*)sp;
    *(float4*)&xs[row_l][seg * 8 + 4] = *(const float4*)(sp + 4);
    if (tid < 128){ gs[tid] = g2[tid]; bs[tid] = b2[tid]; }
  }
  __syncthreads();
  row_stats16(xs, tid, mean_s, rstd_s);
  __syncthreads();
  {
    float mn = mean_s[row_l], rs = rstd_s[row_l];
#pragma unroll
    for (int i = 0; i < 8; ++i){
      int c = seg * 8 + i;
      x2s[row_l][c] = (xs[row_l][c] - mn) * rs * gs[c] + bs[c];
    }
  }
  __syncthreads();

  bf16x8 afr[4];
  build_afr(x2s, lane, afr);
#pragma unroll
  for (int jl = 0; jl < 2; ++jl){
    int nt = w * 2 + jl;
    const bf16x8* wfb = (const bf16x8*)wf + ((size_t)mat1 * 8 + nt) * 4 * 64;
    f32x4 acc = {0, 0, 0, 0};
#pragma unroll
    for (int k0 = 0; k0 < 4; ++k0)
      acc = __builtin_amdgcn_mfma_f32_16x16x32_bf16(afr[k0], wfb[k0 * 64 + lane], acc, 0, 0, 0);
    int c = nt * 16 + mcol;
    float bias = b1f[c];
#pragma unroll
    for (int r = 0; r < 4; ++r)
      y1s[quad * 4 + r][c] = fmaxf(acc[r] + bias, 0.f);
  }
  __syncthreads();

  build_afr(y1s, lane, afr);
#pragma unroll
  for (int jl = 0; jl < 2; ++jl){
    int nt = w * 2 + jl;
    const bf16x8* wfb = (const bf16x8*)wf + ((size_t)(mat1 + 1) * 8 + nt) * 4 * 64;
    f32x4 acc = {0, 0, 0, 0};
#pragma unroll
    for (int k0 = 0; k0 < 4; ++k0)
      acc = __builtin_amdgcn_mfma_f32_16x16x32_bf16(afr[k0], wfb[k0 * 64 + lane], acc, 0, 0, 0);
    int c = nt * 16 + mcol;
    float bias = b2f[c];
#pragma unroll
    for (int r = 0; r < 4; ++r){
      int rl = quad * 4 + r;
      float kp = (ls[rowbase + rl] != 0) ? 1.f : 0.f;
      xos[rl][c] = (x2s[rl][c] + acc[r] + bias) * kp;   // residual adds post-LN2 x2
    }
  }
  __syncthreads();

  if (fuse_qkv){
    if (tid < 128){ gs[tid] = g1[tid]; bs[tid] = b1[tid]; }
    row_stats16(xos, tid, mean_s, rstd_s);
    __syncthreads();
    {
      float mn = mean_s[row_l], rs = rstd_s[row_l];
      float* qp = Q + (rowbase + row_l) * D + seg * 8;
      float4 o0, o1;
      int c0 = seg * 8;
      o0.x=(xos[row_l][c0+0]-mn)*rs*gs[c0+0]+bs[c0+0];
      o0.y=(xos[row_l][c0+1]-mn)*rs*gs[c0+1]+bs[c0+1];
      o0.z=(xos[row_l][c0+2]-mn)*rs*gs[c0+2]+bs[c0+2];
      o0.w=(xos[row_l][c0+3]-mn)*rs*gs[c0+3]+bs[c0+3];
      o1.x=(xos[row_l][c0+4]-mn)*rs*gs[c0+4]+bs[c0+4];
      o1.y=(xos[row_l][c0+5]-mn)*rs*gs[c0+5]+bs[c0+5];
      o1.z=(xos[row_l][c0+6]-mn)*rs*gs[c0+6]+bs[c0+6];
      o1.w=(xos[row_l][c0+7]-mn)*rs*gs[c0+7]+bs[c0+7];
      *(float4*)qp = o0; *(float4*)(qp + 4) = o1;
    }
    bf16x8 afrQ[4], afrX[4];
    build_afr_ln(xos, lane, mean_s, rstd_s, gs, bs, afrQ);
    build_afr(xos, lane, afrX);
#pragma unroll
    for (int jl = 0; jl < 6; ++jl){
      int j = w * 6 + jl;
      int mat = j >> 3, nt = j & 7;
      const bf16x8* wfb = (const bf16x8*)wf + ((size_t)(matq + mat) * 8 + nt) * 4 * 64;
      f32x4 acc = {0, 0, 0, 0};
#pragma unroll
      for (int k0 = 0; k0 < 4; ++k0)
        acc = __builtin_amdgcn_mfma_f32_16x16x32_bf16(mat == 0 ? afrQ[k0] : afrX[k0],
                                                      wfb[k0 * 64 + lane], acc, 0, 0, 0);
      int c = nt * 16 + mcol;
      float bias = (mat == 0 ? bq : mat == 1 ? bk : bv)[c];
#pragma unroll
      for (int r = 0; r < 4; ++r){
        int row = rowbase + quad * 4 + r;
        float v = acc[r] + bias;
        if (mat == 0) write_qA(qA, row, c, v);
        else if (mat == 1) write_kB(kB, row, c, v);
        else write_vB(vB, row, c, v);
      }
    }
  }

  if (fuse_lnf){
    if (tid < 128){ gs[tid] = lg[tid]; bs[tid] = lb[tid]; }
    row_stats16(xos, tid, mean_s, rstd_s);
    __syncthreads();
    float mn = mean_s[row_l], rs = rstd_s[row_l];
    float* op = lf + (rowbase + row_l) * D + seg * 8;
    float4 o0, o1;
    int c0 = seg * 8;
    o0.x=(xos[row_l][c0+0]-mn)*rs*gs[c0+0]+bs[c0+0];
    o0.y=(xos[row_l][c0+1]-mn)*rs*gs[c0+1]+bs[c0+1];
    o0.z=(xos[row_l][c0+2]-mn)*rs*gs[c0+2]+bs[c0+2];
    o0.w=(xos[row_l][c0+3]-mn)*rs*gs[c0+3]+bs[c0+3];
    o1.x=(xos[row_l][c0+4]-mn)*rs*gs[c0+4]+bs[c0+4];
    o1.y=(xos[row_l][c0+5]-mn)*rs*gs[c0+5]+bs[c0+5];
    o1.z=(xos[row_l][c0+6]-mn)*rs*gs[c0+6]+bs[c0+6];
    o1.w=(xos[row_l][c0+7]-mn)*rs*gs[c0+7]+bs[c0+7];
    *(float4*)op = o0; *(float4*)(op + 4) = o1;
  }
}

extern "C" void kernel_launch(void* const* d_in, const int* in_sizes, int n_in,
                              void* d_out, int out_size, void* d_ws, size_t ws_size,
                              hipStream_t stream){
  const int*   ls   = (const int*)d_in[0];
  const float* seqs = (const float*)d_in[1];
  const float* T    = (const float*)d_in[2];
  const float* Wq   = (const float*)d_in[3];
  const float* bq   = (const float*)d_in[4];
  const float* Wk   = (const float*)d_in[5];
  const float* bk   = (const float*)d_in[6];
  const float* Wv   = (const float*)d_in[7];
  const float* bv   = (const float*)d_in[8];
  const float* Wt   = (const float*)d_in[9];
  const float* bt   = (const float*)d_in[10];
  const float* Wtp  = (const float*)d_in[11];
  const float* btp  = (const float*)d_in[12];
  const float* g1   = (const float*)d_in[13];
  const float* b1   = (const float*)d_in[14];
  const float* g2   = (const float*)d_in[15];
  const float* b2   = (const float*)d_in[16];
  const float* W1   = (const float*)d_in[17];
  const float* b1f  = (const float*)d_in[18];
  const float* W2   = (const float*)d_in[19];
  const float* b2f  = (const float*)d_in[20];
  const float* lg   = (const float*)d_in[21];
  const float* lb   = (const float*)d_in[22];

  float* ws    = (float*)d_ws;
  float* Q     = ws;                  // 65536
  float* xr    = Q + 65536;           // 65536
  float* logtw = xr + 65536;          // 2*262144
  unsigned short* bfg = (unsigned short*)(logtw + 2 * 262144);  // 32768
  unsigned short* wf  = bfg + 32768;  // 163840
  unsigned short* qA  = wf + 163840;  // 65536
  unsigned short* kB  = qA + 65536;   // 65536
  unsigned short* vB  = kB + 65536;   // 65536

  float* outF = (float*)d_out;
  float* lf = outF;
  float* w0 = outF + 65536;
  float* w1 = w0 + 1048576;

  k_prep    <<<768, 256, 0, stream>>>(Wt, Wq, Wk, Wv, W1, W2, bfg, wf);
  k_timebias<<<1024, 256, 0, stream>>>(T, bfg, bt, Wtp, btp, logtw);

  // block 0
  k_qkv_m<<<32, 256, 0, stream>>>(seqs, ls, 1, g1, b1, wf, 0, bq, bk, bv,
                                  Q, qA, kB, vB);
  k_attn<<<128, 256, 0, stream>>>(qA, kB, vB, logtw, ls, Q, w0, xr);
  // FFN(block0) fused with LN1+QKV(block1)
  k_ffn_m<<<32, 256, 0, stream>>>(xr, ls, g2, b2, wf, 3, b1f, b2f,
                                  1, g1 + D, b1 + D, 5, bq + D, bk + D, bv + D,
                                  Q, qA, kB, vB,
                                  0, lg, lb, lf);
  // block 1
  k_attn<<<128, 256, 0, stream>>>(qA, kB, vB, logtw + L * L, ls, Q, w1, xr);
  k_ffn_m<<<32, 256, 0, stream>>>(xr, ls, g2 + D, b2 + D, wf, 8, b1f + D, b2f + D,
                                  0, g1, b1, 0, bq, bk, bv,
                                  Q, qA, kB, vB,
                                  1, lg, lb, lf);
}

// Round 5
// 276.559 us; speedup vs baseline: 1.5419x; 1.0816x over previous
//
#include <hip/hip_runtime.h>

#define L 512
#define D 128
#define H 4
#define HD 32
#define XLD 132   // padded LDS leading dim (floats) to break 16-way bank conflicts

typedef __bf16 bf16x8 __attribute__((ext_vector_type(8)));
typedef float  f32x4  __attribute__((ext_vector_type(4)));

__device__ __forceinline__ unsigned short bfbits(float v){
  __bf16 h = (__bf16)v; unsigned short u; __builtin_memcpy(&u, &h, 2); return u;
}
__device__ __forceinline__ bf16x8 cvt8(float4 a0, float4 a1){
  bf16x8 r;
  r[0] = (__bf16)a0.x; r[1] = (__bf16)a0.y; r[2] = (__bf16)a0.z; r[3] = (__bf16)a0.w;
  r[4] = (__bf16)a1.x; r[5] = (__bf16)a1.y; r[6] = (__bf16)a1.z; r[7] = (__bf16)a1.w;
  return r;
}

// -------- fragment-write helpers (thread owns value at (row, c)) ------------
__device__ __forceinline__ void write_qA(unsigned short* qA, int row, int c, float v){
  int qt = row >> 4, m = row & 15;
  int h = c >> 5, cc = c & 31;
  qA[(((qt * 4 + h) * 64) + (cc >> 3) * 16 + m) * 8 + (cc & 7)] = bfbits(v);
}
__device__ __forceinline__ void write_kB(unsigned short* kB, int row, int c, float v){
  int h = c >> 5, cc = c & 31;
  int nt = row >> 4;
  kB[((h * 32 + nt) * 64 + (cc >> 3) * 16 + (row & 15)) * 8 + (cc & 7)] = bfbits(v);
}
__device__ __forceinline__ void write_vB(unsigned short* vB, int row, int c, float v){
  int h = c >> 5, cc = c & 31;
  int kk = row >> 5, qv = (row >> 3) & 3, jv = row & 7;
  int nt = cc >> 4;
  vB[(((h * 16 + kk) * 2 + nt) * 64 + qv * 16 + (cc & 15)) * 8 + jv] = bfbits(v);
}

// ---- per-16-row stats (block of 256 threads; thread t: row=t>>4, seg=t&15) --
__device__ __forceinline__ void row_stats16(const float (*buf)[XLD], int tid,
                                            float* mean_s, float* rstd_s){
  int row_l = tid >> 4, seg = tid & 15;
  const float* p = &buf[row_l][seg * 8];
  float4 f0 = *(const float4*)p, f1 = *(const float4*)(p + 4);
  float sum = f0.x + f0.y + f0.z + f0.w + f1.x + f1.y + f1.z + f1.w;
  float sq  = f0.x*f0.x + f0.y*f0.y + f0.z*f0.z + f0.w*f0.w
            + f1.x*f1.x + f1.y*f1.y + f1.z*f1.z + f1.w*f1.w;
#pragma unroll
  for (int o = 1; o < 16; o <<= 1){ sum += __shfl_xor(sum, o); sq += __shfl_xor(sq, o); }
  if (seg == 0){
    float mn = sum * (1.f / 128.f);
    mean_s[row_l] = mn;
    rstd_s[row_l] = rsqrtf(fmaxf(sq * (1.f / 128.f) - mn * mn, 0.f) + 1e-8f);
  }
}

// ---- A-fragment builders from a 16x128 LDS tile ----------------------------
__device__ __forceinline__ void build_afr(const float (*buf)[XLD], int lane, bf16x8* afr){
  int m = lane & 15, quad = lane >> 4;
#pragma unroll
  for (int k0 = 0; k0 < 4; ++k0){
    const float* p = &buf[m][k0 * 32 + quad * 8];
    afr[k0] = cvt8(*(const float4*)p, *(const float4*)(p + 4));
  }
}
__device__ __forceinline__ void build_afr_ln(const float (*buf)[XLD], int lane,
    const float* mean_s, const float* rstd_s,
    const float* __restrict__ g, const float* __restrict__ b, bf16x8* afr){
  int m = lane & 15, quad = lane >> 4;
  float mn = mean_s[m], rs = rstd_s[m];
#pragma unroll
  for (int k0 = 0; k0 < 4; ++k0){
    int c0 = k0 * 32 + quad * 8;
    const float* p = &buf[m][c0];
    float4 a0 = *(const float4*)p, a1 = *(const float4*)(p + 4);
    float q[8];
    q[0]=(a0.x-mn)*rs*g[c0+0]+b[c0+0]; q[1]=(a0.y-mn)*rs*g[c0+1]+b[c0+1];
    q[2]=(a0.z-mn)*rs*g[c0+2]+b[c0+2]; q[3]=(a0.w-mn)*rs*g[c0+3]+b[c0+3];
    q[4]=(a1.x-mn)*rs*g[c0+4]+b[c0+4]; q[5]=(a1.y-mn)*rs*g[c0+5]+b[c0+5];
    q[6]=(a1.z-mn)*rs*g[c0+6]+b[c0+6]; q[7]=(a1.w-mn)*rs*g[c0+7]+b[c0+7];
    bf16x8 r;
    r[0]=(__bf16)q[0]; r[1]=(__bf16)q[1]; r[2]=(__bf16)q[2]; r[3]=(__bf16)q[3];
    r[4]=(__bf16)q[4]; r[5]=(__bf16)q[5]; r[6]=(__bf16)q[6]; r[7]=(__bf16)q[7];
    afr[k0] = r;
  }
}

// ------------- prep: swizzle Wt (timebias layout) + 10 GEMM weights ---------
// wf layout (bf16x8 units): [((mat*8 + nt)*4 + k0)*64 + lane], mat = blk*5 + {q,k,v,W1,W2}
__global__ void k_prep(const float* __restrict__ Wt,
                       const float* __restrict__ Wq, const float* __restrict__ Wk,
                       const float* __restrict__ Wv, const float* __restrict__ W1,
                       const float* __restrict__ W2,
                       unsigned short* __restrict__ bfg, unsigned short* __restrict__ wf){
  int idx = blockIdx.x * 256 + threadIdx.x;      // 196608 threads
  if (idx < 32768){
    int jj   = idx & 7;
    int lane = (idx >> 3) & 63;
    int k0   = (idx >> 9) & 3;
    int nt   = idx >> 11;
    int d    = k0 * 32 + (lane >> 4) * 8 + jj;
    int col  = (nt & 7) * 16 + (lane & 15);
    int blk  = nt >> 3;
    bfg[idx] = bfbits(Wt[blk * D * D + d * D + col]);
  } else {
    int i2 = idx - 32768;
    int jj = i2 & 7, lane = (i2 >> 3) & 63, k0 = (i2 >> 9) & 3, nt = (i2 >> 11) & 7;
    int mat = i2 >> 14;                          // 0..9
    int blk = mat / 5, m5 = mat % 5;
    const float* W = (m5 == 0 ? Wq : m5 == 1 ? Wk : m5 == 2 ? Wv : m5 == 3 ? W1 : W2)
                     + blk * D * D;
    int d = k0 * 32 + (lane >> 4) * 8 + jj;
    int col = nt * 16 + (lane & 15);
    wf[i2] = bfbits(W[d * D + col]);
  }
}

// ---------------- time-bias: logtw[blk][q][k] = log(sigmoid(...)) -----------
// 32 KB LDS per pass (one weight-block at a time); (256,2) so the 64-VGPR
// afr slab is NOT spilled (R4 post-mortem: (256,4) capped VGPR=64 -> 24 MB spill).
__global__ __launch_bounds__(256, 2) void k_timebias(
    const float* __restrict__ T, const unsigned short* __restrict__ bfg,
    const float* __restrict__ bt, const float* __restrict__ wtp,
    const float* __restrict__ btp, float* __restrict__ logtw){
  __shared__ __align__(16) unsigned short bsh[16384];   // 32 KB
  __shared__ float bts[128], wtps[128];
  int tid = threadIdx.x;
  int lane = tid & 63, w = tid >> 6;
  int quad = lane >> 4, m = lane & 15;
  const bf16x8* bls = (const bf16x8*)bsh;
  int wbase = blockIdx.x * 256 + w * 64;

  bf16x8 afr[4][4];
#pragma unroll
  for (int mt = 0; mt < 4; ++mt){
    const float* tp = T + (size_t)(wbase + mt * 16 + m) * D + quad * 8;
#pragma unroll
    for (int k0 = 0; k0 < 4; ++k0){
      float4 f0 = *(const float4*)(tp + k0 * 32);
      float4 f1 = *(const float4*)(tp + k0 * 32 + 4);
      afr[mt][k0] = cvt8(f0, f1);
    }
  }

#pragma unroll
  for (int blk = 0; blk < 2; ++blk){
    if (blk) __syncthreads();                   // protect bsh overwrite
    {
      const uint4* g = (const uint4*)(bfg + blk * 16384);
      uint4* s = (uint4*)bsh;
#pragma unroll
      for (int i = 0; i < 8; ++i) s[tid + i * 256] = g[tid + i * 256];
      if (tid < 128){ bts[tid] = bt[blk * 128 + tid]; wtps[tid] = wtp[blk * 128 + tid]; }
    }
    __syncthreads();

    f32x4 rs[4] = {{0,0,0,0},{0,0,0,0},{0,0,0,0},{0,0,0,0}};
#pragma unroll
    for (int ntl = 0; ntl < 8; ++ntl){
      f32x4 acc[4] = {{0,0,0,0},{0,0,0,0},{0,0,0,0},{0,0,0,0}};
#pragma unroll
      for (int k0 = 0; k0 < 4; ++k0){
        bf16x8 b = bls[(ntl * 4 + k0) * 64 + lane];
#pragma unroll
        for (int mt = 0; mt < 4; ++mt)
          acc[mt] = __builtin_amdgcn_mfma_f32_16x16x32_bf16(afr[mt][k0], b, acc[mt], 0, 0, 0);
      }
      float btv = bts[ntl * 16 + m];
      float wtv = wtps[ntl * 16 + m];
#pragma unroll
      for (int mt = 0; mt < 4; ++mt)
#pragma unroll
        for (int r = 0; r < 4; ++r)
          rs[mt][r] += fmaxf(acc[mt][r] + btv, 0.f) * wtv;
    }
#pragma unroll
    for (int mt = 0; mt < 4; ++mt)
#pragma unroll
      for (int r = 0; r < 4; ++r){
        float v = rs[mt][r];
        v += __shfl_xor(v, 1); v += __shfl_xor(v, 2);
        v += __shfl_xor(v, 4); v += __shfl_xor(v, 8);
        rs[mt][r] = v;
      }
    if (m == 0){
      float bp = btp[blk];
      float* out = logtw + blk * (L * L);
#pragma unroll
      for (int mt = 0; mt < 4; ++mt){
        float4 o;
        float s0 = rs[mt][0] + bp; o.x = -__logf(1.f + __expf(-s0));
        float s1 = rs[mt][1] + bp; o.y = -__logf(1.f + __expf(-s1));
        float s2 = rs[mt][2] + bp; o.z = -__logf(1.f + __expf(-s2));
        float s3 = rs[mt][3] + bp; o.w = -__logf(1.f + __expf(-s3));
        *(float4*)(out + wbase + mt * 16 + quad * 4) = o;
      }
    }
  }
}

// ------ MFMA LN1+QKV: block = (16 rows, mat), 4 waves split 8 ntile-jobs ----
__global__ __launch_bounds__(256) void k_qkv_m(
    const float* __restrict__ src, const int* __restrict__ ls, int domask,
    const float* __restrict__ g1, const float* __restrict__ b1,
    const unsigned short* __restrict__ wf, int matq,
    const float* __restrict__ bq, const float* __restrict__ bk,
    const float* __restrict__ bv,
    float* __restrict__ Q, unsigned short* __restrict__ qA,
    unsigned short* __restrict__ kB, unsigned short* __restrict__ vB){
  __shared__ float xs[16][XLD];
  __shared__ float mean_s[16], rstd_s[16];
  __shared__ float g1s[128], b1s[128];
  int tid = threadIdx.x, rowbase = blockIdx.x * 16;
  int mat = blockIdx.y;                          // 0=q,1=k,2=v
  int row_l = tid >> 4, seg = tid & 15;

  const float* sp = src + (rowbase + row_l) * D + seg * 8;
  float4 f0 = *(const float4*)sp, f1 = *(const float4*)(sp + 4);
  if (domask && ls[rowbase + row_l] == 0){
    f0 = make_float4(0,0,0,0); f1 = make_float4(0,0,0,0);
  }
  *(float4*)&xs[row_l][seg * 8] = f0;
  *(float4*)&xs[row_l][seg * 8 + 4] = f1;
  if (mat == 0 && tid < 128){ g1s[tid] = g1[tid]; b1s[tid] = b1[tid]; }
  __syncthreads();
  if (mat == 0){
    row_stats16(xs, tid, mean_s, rstd_s);
    __syncthreads();
    // write Q (post-LN1, fp32) for the attention residual
    float mn = mean_s[row_l], rs = rstd_s[row_l];
    float* qp = Q + (rowbase + row_l) * D + seg * 8;
    float4 o0, o1;
    int c0 = seg * 8;
    o0.x=(f0.x-mn)*rs*g1s[c0+0]+b1s[c0+0]; o0.y=(f0.y-mn)*rs*g1s[c0+1]+b1s[c0+1];
    o0.z=(f0.z-mn)*rs*g1s[c0+2]+b1s[c0+2]; o0.w=(f0.w-mn)*rs*g1s[c0+3]+b1s[c0+3];
    o1.x=(f1.x-mn)*rs*g1s[c0+4]+b1s[c0+4]; o1.y=(f1.y-mn)*rs*g1s[c0+5]+b1s[c0+5];
    o1.z=(f1.z-mn)*rs*g1s[c0+6]+b1s[c0+6]; o1.w=(f1.w-mn)*rs*g1s[c0+7]+b1s[c0+7];
    *(float4*)qp = o0; *(float4*)(qp + 4) = o1;
  }

  int lane = tid & 63, w = tid >> 6;
  int quad = lane >> 4, mcol = lane & 15;
  bf16x8 afr[4];
  if (mat == 0) build_afr_ln(xs, lane, mean_s, rstd_s, g1s, b1s, afr);
  else          build_afr(xs, lane, afr);

  const float* bias_v = (mat == 0 ? bq : mat == 1 ? bk : bv);
#pragma unroll
  for (int jl = 0; jl < 2; ++jl){
    int nt = w * 2 + jl;
    const bf16x8* wfb = (const bf16x8*)wf + ((size_t)(matq + mat) * 8 + nt) * 4 * 64;
    f32x4 acc = {0, 0, 0, 0};
#pragma unroll
    for (int k0 = 0; k0 < 4; ++k0)
      acc = __builtin_amdgcn_mfma_f32_16x16x32_bf16(afr[k0], wfb[k0 * 64 + lane], acc, 0, 0, 0);
    int c = nt * 16 + mcol;
    float bias = bias_v[c];
#pragma unroll
    for (int r = 0; r < 4; ++r){
      int row = rowbase + quad * 4 + r;
      float v = acc[r] + bias;
      if (mat == 0) write_qA(qA, row, c, v);
      else if (mat == 1) write_kB(kB, row, c, v);
      else write_vB(vB, row, c, v);
    }
  }
}

// ---------------- MFMA attention: block = (qtile of 16 rows, head) ----------
__global__ __launch_bounds__(256) void k_attn(
    const unsigned short* __restrict__ qA, const unsigned short* __restrict__ kB,
    const unsigned short* __restrict__ vB, const float* __restrict__ logtw,
    const int* __restrict__ ls, const float* __restrict__ Q,
    float* __restrict__ wout, float* __restrict__ xr){
  __shared__ __align__(16) unsigned short pa[16 * 64 * 8];
  __shared__ float pvp[4][2][64][4];
  __shared__ float smax[4][16], ssum[4][16];
  int qt = blockIdx.x >> 2, h = blockIdx.x & 3;
  int tid = threadIdx.x, lane = tid & 63, w = tid >> 6;
  int quad = lane >> 4, mcol = lane & 15;
  const float RS = 0.17677669529663687f;

  bf16x8 qf = ((const bf16x8*)qA)[(qt * 4 + h) * 64 + lane];

  f32x4 acc[8];
#pragma unroll
  for (int nt8 = 0; nt8 < 8; ++nt8){
    bf16x8 bf = ((const bf16x8*)kB)[(h * 32 + w * 8 + nt8) * 64 + lane];
    f32x4 z = {0, 0, 0, 0};
    acc[nt8] = __builtin_amdgcn_mfma_f32_16x16x32_bf16(qf, bf, z, 0, 0, 0);
  }

  float e[8][4];
  float mx4[4] = {-3e38f, -3e38f, -3e38f, -3e38f};
#pragma unroll
  for (int nt8 = 0; nt8 < 8; ++nt8){
    int col = w * 128 + nt8 * 16 + mcol;
#pragma unroll
    for (int r = 0; r < 4; ++r){
      int row = qt * 16 + quad * 4 + r;
      float sv = (acc[nt8][r] + logtw[row * L + col]) * RS;
      sv = (col <= row) ? sv : -3e38f;
      e[nt8][r] = sv;
      mx4[r] = fmaxf(mx4[r], sv);
    }
  }
#pragma unroll
  for (int r = 0; r < 4; ++r){
    float v = mx4[r];
    v = fmaxf(v, __shfl_xor(v, 1)); v = fmaxf(v, __shfl_xor(v, 2));
    v = fmaxf(v, __shfl_xor(v, 4)); v = fmaxf(v, __shfl_xor(v, 8));
    mx4[r] = v;
  }
  if (mcol == 0){
#pragma unroll
    for (int r = 0; r < 4; ++r) smax[w][quad * 4 + r] = mx4[r];
  }
  __syncthreads();
  float mxr[4], sum4[4] = {0, 0, 0, 0};
#pragma unroll
  for (int r = 0; r < 4; ++r){
    int rr = quad * 4 + r;
    mxr[r] = fmaxf(fmaxf(smax[0][rr], smax[1][rr]), fmaxf(smax[2][rr], smax[3][rr]));
  }
#pragma unroll
  for (int nt8 = 0; nt8 < 8; ++nt8)
#pragma unroll
    for (int r = 0; r < 4; ++r){
      float sv = e[nt8][r];
      float ev = (sv > -1e38f) ? __expf(sv - mxr[r]) : 0.f;
      e[nt8][r] = ev;
      sum4[r] += ev;
    }
#pragma unroll
  for (int r = 0; r < 4; ++r){
    float v = sum4[r];
    v += __shfl_xor(v, 1); v += __shfl_xor(v, 2);
    v += __shfl_xor(v, 4); v += __shfl_xor(v, 8);
    sum4[r] = v;
  }
  if (mcol == 0){
#pragma unroll
    for (int r = 0; r < 4; ++r) ssum[w][quad * 4 + r] = sum4[r];
  }
  __syncthreads();
  float inv[4]; int padr[4];
#pragma unroll
  for (int r = 0; r < 4; ++r){
    int rr = quad * 4 + r;
    inv[r] = 1.f / (ssum[0][rr] + ssum[1][rr] + ssum[2][rr] + ssum[3][rr]);
    padr[r] = (ls[qt * 16 + rr] == 0);
  }
#pragma unroll
  for (int nt8 = 0; nt8 < 8; ++nt8){
    int col = w * 128 + nt8 * 16 + mcol;
    int kk = col >> 5, qk = (col >> 3) & 3, jj = col & 7;
#pragma unroll
    for (int r = 0; r < 4; ++r){
      int rl = quad * 4 + r;
      float wv = padr[r] ? (1.f / 512.f) : e[nt8][r] * inv[r];
      wout[h * (L * L) + (qt * 16 + rl) * L + col] = wv;
      pa[(kk * 64 + qk * 16 + rl) * 8 + jj] = bfbits(wv);
    }
  }

  f32x4 pacc[2] = {{0,0,0,0},{0,0,0,0}};
#pragma unroll
  for (int kk4 = 0; kk4 < 4; ++kk4){
    int kk = w * 4 + kk4;
    bf16x8 af = ((const bf16x8*)pa)[kk * 64 + lane];
#pragma unroll
    for (int nt = 0; nt < 2; ++nt){
      bf16x8 bf = ((const bf16x8*)vB)[((h * 16 + kk) * 2 + nt) * 64 + lane];
      pacc[nt] = __builtin_amdgcn_mfma_f32_16x16x32_bf16(af, bf, pacc[nt], 0, 0, 0);
    }
  }
#pragma unroll
  for (int nt = 0; nt < 2; ++nt)
#pragma unroll
    for (int r = 0; r < 4; ++r) pvp[w][nt][lane][r] = pacc[nt][r];
  __syncthreads();
  if (w < 2){
    int nt = w;
#pragma unroll
    for (int r = 0; r < 4; ++r){
      float o = pvp[0][nt][lane][r] + pvp[1][nt][lane][r]
              + pvp[2][nt][lane][r] + pvp[3][nt][lane][r];
      int row = qt * 16 + quad * 4 + r;
      int cg = h * HD + nt * 16 + mcol;
      xr[row * D + cg] = Q[row * D + cg] + o;
    }
  }
}

// ---- MFMA LN2+FFN (+keep); optional fused LN1+QKV of next block / final LN --
__global__ __launch_bounds__(256) void k_ffn_m(
    const float* __restrict__ xr, const int* __restrict__ ls,
    const float* __restrict__ g2, const float* __restrict__ b2,
    const unsigned short* __restrict__ wf, int mat1,
    const float* __restrict__ b1f, const float* __restrict__ b2f,
    int fuse_qkv, const float* __restrict__ g1, const float* __restrict__ b1,
    int matq, const float* __restrict__ bq, const float* __restrict__ bk,
    const float* __restrict__ bv,
    float* __restrict__ Q, unsigned short* __restrict__ qA,
    unsigned short* __restrict__ kB, unsigned short* __restrict__ vB,
    int fuse_lnf, const float* __restrict__ lg, const float* __restrict__ lb,
    float* __restrict__ lf){
  __shared__ float xs[16][XLD];
  __shared__ float x2s[16][XLD];
  __shared__ float y1s[16][XLD];
  __shared__ float xos[16][XLD];
  __shared__ float mean_s[16], rstd_s[16];
  __shared__ float gs[128], bs[128];
  int tid = threadIdx.x, rowbase = blockIdx.x * 16;
  int row_l = tid >> 4, seg = tid & 15;
  int lane = tid & 63, w = tid >> 6;
  int quad = lane >> 4, mcol = lane & 15;

  {
    const float* sp = xr + (rowbase + row_l) * D + seg * 8;
    *(float4*)&xs[row_l][seg * 8] = *(const float4*)sp;
    *(float4*)&xs[row_l][seg * 8 + 4] = *(const float4*)(sp + 4);
    if (tid < 128){ gs[tid] = g2[tid]; bs[tid] = b2[tid]; }
  }
  __syncthreads();
  row_stats16(xs, tid, mean_s, rstd_s);
  __syncthreads();
  {
    float mn = mean_s[row_l], rs = rstd_s[row_l];
#pragma unroll
    for (int i = 0; i < 8; ++i){
      int c = seg * 8 + i;
      x2s[row_l][c] = (xs[row_l][c] - mn) * rs * gs[c] + bs[c];
    }
  }
  __syncthreads();

  bf16x8 afr[4];
  build_afr(x2s, lane, afr);
#pragma unroll
  for (int jl = 0; jl < 2; ++jl){
    int nt = w * 2 + jl;
    const bf16x8* wfb = (const bf16x8*)wf + ((size_t)mat1 * 8 + nt) * 4 * 64;
    f32x4 acc = {0, 0, 0, 0};
#pragma unroll
    for (int k0 = 0; k0 < 4; ++k0)
      acc = __builtin_amdgcn_mfma_f32_16x16x32_bf16(afr[k0], wfb[k0 * 64 + lane], acc, 0, 0, 0);
    int c = nt * 16 + mcol;
    float bias = b1f[c];
#pragma unroll
    for (int r = 0; r < 4; ++r)
      y1s[quad * 4 + r][c] = fmaxf(acc[r] + bias, 0.f);
  }
  __syncthreads();

  build_afr(y1s, lane, afr);
#pragma unroll
  for (int jl = 0; jl < 2; ++jl){
    int nt = w * 2 + jl;
    const bf16x8* wfb = (const bf16x8*)wf + ((size_t)(mat1 + 1) * 8 + nt) * 4 * 64;
    f32x4 acc = {0, 0, 0, 0};
#pragma unroll
    for (int k0 = 0; k0 < 4; ++k0)
      acc = __builtin_amdgcn_mfma_f32_16x16x32_bf16(afr[k0], wfb[k0 * 64 + lane], acc, 0, 0, 0);
    int c = nt * 16 + mcol;
    float bias = b2f[c];
#pragma unroll
    for (int r = 0; r < 4; ++r){
      int rl = quad * 4 + r;
      float kp = (ls[rowbase + rl] != 0) ? 1.f : 0.f;
      xos[rl][c] = (x2s[rl][c] + acc[r] + bias) * kp;   // residual adds post-LN2 x2
    }
  }
  __syncthreads();

  if (fuse_qkv){
    if (tid < 128){ gs[tid] = g1[tid]; bs[tid] = b1[tid]; }
    row_stats16(xos, tid, mean_s, rstd_s);
    __syncthreads();
    {
      float mn = mean_s[row_l], rs = rstd_s[row_l];
      float* qp = Q + (rowbase + row_l) * D + seg * 8;
      float4 o0, o1;
      int c0 = seg * 8;
      o0.x=(xos[row_l][c0+0]-mn)*rs*gs[c0+0]+bs[c0+0];
      o0.y=(xos[row_l][c0+1]-mn)*rs*gs[c0+1]+bs[c0+1];
      o0.z=(xos[row_l][c0+2]-mn)*rs*gs[c0+2]+bs[c0+2];
      o0.w=(xos[row_l][c0+3]-mn)*rs*gs[c0+3]+bs[c0+3];
      o1.x=(xos[row_l][c0+4]-mn)*rs*gs[c0+4]+bs[c0+4];
      o1.y=(xos[row_l][c0+5]-mn)*rs*gs[c0+5]+bs[c0+5];
      o1.z=(xos[row_l][c0+6]-mn)*rs*gs[c0+6]+bs[c0+6];
      o1.w=(xos[row_l][c0+7]-mn)*rs*gs[c0+7]+bs[c0+7];
      *(float4*)qp = o0; *(float4*)(qp + 4) = o1;
    }
    bf16x8 afrQ[4], afrX[4];
    build_afr_ln(xos, lane, mean_s, rstd_s, gs, bs, afrQ);
    build_afr(xos, lane, afrX);
#pragma unroll
    for (int jl = 0; jl < 6; ++jl){
      int j = w * 6 + jl;
      int mat = j >> 3, nt = j & 7;
      const bf16x8* wfb = (const bf16x8*)wf + ((size_t)(matq + mat) * 8 + nt) * 4 * 64;
      f32x4 acc = {0, 0, 0, 0};
#pragma unroll
      for (int k0 = 0; k0 < 4; ++k0)
        acc = __builtin_amdgcn_mfma_f32_16x16x32_bf16(mat == 0 ? afrQ[k0] : afrX[k0],
                                                      wfb[k0 * 64 + lane], acc, 0, 0, 0);
      int c = nt * 16 + mcol;
      float bias = (mat == 0 ? bq : mat == 1 ? bk : bv)[c];
#pragma unroll
      for (int r = 0; r < 4; ++r){
        int row = rowbase + quad * 4 + r;
        float v = acc[r] + bias;
        if (mat == 0) write_qA(qA, row, c, v);
        else if (mat == 1) write_kB(kB, row, c, v);
        else write_vB(vB, row, c, v);
      }
    }
  }

  if (fuse_lnf){
    if (tid < 128){ gs[tid] = lg[tid]; bs[tid] = lb[tid]; }
    row_stats16(xos, tid, mean_s, rstd_s);
    __syncthreads();
    float mn = mean_s[row_l], rs = rstd_s[row_l];
    float* op = lf + (rowbase + row_l) * D + seg * 8;
    float4 o0, o1;
    int c0 = seg * 8;
    o0.x=(xos[row_l][c0+0]-mn)*rs*gs[c0+0]+bs[c0+0];
    o0.y=(xos[row_l][c0+1]-mn)*rs*gs[c0+1]+bs[c0+1];
    o0.z=(xos[row_l][c0+2]-mn)*rs*gs[c0+2]+bs[c0+2];
    o0.w=(xos[row_l][c0+3]-mn)*rs*gs[c0+3]+bs[c0+3];
    o1.x=(xos[row_l][c0+4]-mn)*rs*gs[c0+4]+bs[c0+4];
    o1.y=(xos[row_l][c0+5]-mn)*rs*gs[c0+5]+bs[c0+5];
    o1.z=(xos[row_l][c0+6]-mn)*rs*gs[c0+6]+bs[c0+6];
    o1.w=(xos[row_l][c0+7]-mn)*rs*gs[c0+7]+bs[c0+7];
    *(float4*)op = o0; *(float4*)(op + 4) = o1;
  }
}

extern "C" void kernel_launch(void* const* d_in, const int* in_sizes, int n_in,
                              void* d_out, int out_size, void* d_ws, size_t ws_size,
                              hipStream_t stream){
  const int*   ls   = (const int*)d_in[0];
  const float* seqs = (const float*)d_in[1];
  const float* T    = (const float*)d_in[2];
  const float* Wq   = (const float*)d_in[3];
  const float* bq   = (const float*)d_in[4];
  const float* Wk   = (const float*)d_in[5];
  const float* bk   = (const float*)d_in[6];
  const float* Wv   = (const float*)d_in[7];
  const float* bv   = (const float*)d_in[8];
  const float* Wt   = (const float*)d_in[9];
  const float* bt   = (const float*)d_in[10];
  const float* Wtp  = (const float*)d_in[11];
  const float* btp  = (const float*)d_in[12];
  const float* g1   = (const float*)d_in[13];
  const float* b1   = (const float*)d_in[14];
  const float* g2   = (const float*)d_in[15];
  const float* b2   = (const float*)d_in[16];
  const float* W1   = (const float*)d_in[17];
  const float* b1f  = (const float*)d_in[18];
  const float* W2   = (const float*)d_in[19];
  const float* b2f  = (const float*)d_in[20];
  const float* lg   = (const float*)d_in[21];
  const float* lb   = (const float*)d_in[22];

  float* ws    = (float*)d_ws;
  float* Q     = ws;                  // 65536
  float* xr    = Q + 65536;           // 65536
  float* logtw = xr + 65536;          // 2*262144
  unsigned short* bfg = (unsigned short*)(logtw + 2 * 262144);  // 32768
  unsigned short* wf  = bfg + 32768;  // 163840
  unsigned short* qA  = wf + 163840;  // 65536
  unsigned short* kB  = qA + 65536;   // 65536
  unsigned short* vB  = kB + 65536;   // 65536

  float* outF = (float*)d_out;
  float* lf = outF;
  float* w0 = outF + 65536;
  float* w1 = w0 + 1048576;

  k_prep    <<<768, 256, 0, stream>>>(Wt, Wq, Wk, Wv, W1, W2, bfg, wf);
  k_timebias<<<1024, 256, 0, stream>>>(T, bfg, bt, Wtp, btp, logtw);

  // block 0
  k_qkv_m<<<dim3(32, 3), 256, 0, stream>>>(seqs, ls, 1, g1, b1, wf, 0, bq, bk, bv,
                                           Q, qA, kB, vB);
  k_attn<<<128, 256, 0, stream>>>(qA, kB, vB, logtw, ls, Q, w0, xr);
  // FFN(block0) fused with LN1+QKV(block1)
  k_ffn_m<<<32, 256, 0, stream>>>(xr, ls, g2, b2, wf, 3, b1f, b2f,
                                  1, g1 + D, b1 + D, 5, bq + D, bk + D, bv + D,
                                  Q, qA, kB, vB,
                                  0, lg, lb, lf);
  // block 1
  k_attn<<<128, 256, 0, stream>>>(qA, kB, vB, logtw + L * L, ls, Q, w1, xr);
  k_ffn_m<<<32, 256, 0, stream>>>(xr, ls, g2 + D, b2 + D, wf, 8, b1f + D, b2f + D,
                                  0, g1, b1, 0, bq, bk, bv,
                                  Q, qA, kB, vB,
                                  1, lg, lb, lf);
}

// Round 6
// 267.901 us; speedup vs baseline: 1.5917x; 1.0323x over previous
//
#include <hip/hip_runtime.h>

#define L 512
#define D 128
#define H 4
#define HD 32
#define XLD 132   // padded LDS leading dim (floats) to break 16-way bank conflicts
#define NTB 576   // causal timebias blocks (2304 strips / 4 waves)

typedef __bf16 bf16x8 __attribute__((ext_vector_type(8)));
typedef float  f32x4  __attribute__((ext_vector_type(4)));

__device__ __forceinline__ unsigned short bfbits(float v){
  __bf16 h = (__bf16)v; unsigned short u; __builtin_memcpy(&u, &h, 2); return u;
}
__device__ __forceinline__ bf16x8 cvt8(float4 a0, float4 a1){
  bf16x8 r;
  r[0] = (__bf16)a0.x; r[1] = (__bf16)a0.y; r[2] = (__bf16)a0.z; r[3] = (__bf16)a0.w;
  r[4] = (__bf16)a1.x; r[5] = (__bf16)a1.y; r[6] = (__bf16)a1.z; r[7] = (__bf16)a1.w;
  return r;
}

// -------- fragment-write helpers (thread owns value at (row, c)) ------------
__device__ __forceinline__ void write_qA(unsigned short* qA, int row, int c, float v){
  int qt = row >> 4, m = row & 15;
  int h = c >> 5, cc = c & 31;
  qA[(((qt * 4 + h) * 64) + (cc >> 3) * 16 + m) * 8 + (cc & 7)] = bfbits(v);
}
__device__ __forceinline__ void write_kB(unsigned short* kB, int row, int c, float v){
  int h = c >> 5, cc = c & 31;
  int nt = row >> 4;
  kB[((h * 32 + nt) * 64 + (cc >> 3) * 16 + (row & 15)) * 8 + (cc & 7)] = bfbits(v);
}
__device__ __forceinline__ void write_vB(unsigned short* vB, int row, int c, float v){
  int h = c >> 5, cc = c & 31;
  int kk = row >> 5, qv = (row >> 3) & 3, jv = row & 7;
  int nt = cc >> 4;
  vB[(((h * 16 + kk) * 2 + nt) * 64 + qv * 16 + (cc & 15)) * 8 + jv] = bfbits(v);
}

// ---- per-16-row stats (block of 256 threads; thread t: row=t>>4, seg=t&15) --
__device__ __forceinline__ void row_stats16(const float (*buf)[XLD], int tid,
                                            float* mean_s, float* rstd_s){
  int row_l = tid >> 4, seg = tid & 15;
  const float* p = &buf[row_l][seg * 8];
  float4 f0 = *(const float4*)p, f1 = *(const float4*)(p + 4);
  float sum = f0.x + f0.y + f0.z + f0.w + f1.x + f1.y + f1.z + f1.w;
  float sq  = f0.x*f0.x + f0.y*f0.y + f0.z*f0.z + f0.w*f0.w
            + f1.x*f1.x + f1.y*f1.y + f1.z*f1.z + f1.w*f1.w;
#pragma unroll
  for (int o = 1; o < 16; o <<= 1){ sum += __shfl_xor(sum, o); sq += __shfl_xor(sq, o); }
  if (seg == 0){
    float mn = sum * (1.f / 128.f);
    mean_s[row_l] = mn;
    rstd_s[row_l] = rsqrtf(fmaxf(sq * (1.f / 128.f) - mn * mn, 0.f) + 1e-8f);
  }
}

// ---- A-fragment builders from a 16x128 LDS tile ----------------------------
__device__ __forceinline__ void build_afr(const float (*buf)[XLD], int lane, bf16x8* afr){
  int m = lane & 15, quad = lane >> 4;
#pragma unroll
  for (int k0 = 0; k0 < 4; ++k0){
    const float* p = &buf[m][k0 * 32 + quad * 8];
    afr[k0] = cvt8(*(const float4*)p, *(const float4*)(p + 4));
  }
}
__device__ __forceinline__ void build_afr_ln(const float (*buf)[XLD], int lane,
    const float* mean_s, const float* rstd_s,
    const float* __restrict__ g, const float* __restrict__ b, bf16x8* afr){
  int m = lane & 15, quad = lane >> 4;
  float mn = mean_s[m], rs = rstd_s[m];
#pragma unroll
  for (int k0 = 0; k0 < 4; ++k0){
    int c0 = k0 * 32 + quad * 8;
    const float* p = &buf[m][c0];
    float4 a0 = *(const float4*)p, a1 = *(const float4*)(p + 4);
    float q[8];
    q[0]=(a0.x-mn)*rs*g[c0+0]+b[c0+0]; q[1]=(a0.y-mn)*rs*g[c0+1]+b[c0+1];
    q[2]=(a0.z-mn)*rs*g[c0+2]+b[c0+2]; q[3]=(a0.w-mn)*rs*g[c0+3]+b[c0+3];
    q[4]=(a1.x-mn)*rs*g[c0+4]+b[c0+4]; q[5]=(a1.y-mn)*rs*g[c0+5]+b[c0+5];
    q[6]=(a1.z-mn)*rs*g[c0+6]+b[c0+6]; q[7]=(a1.w-mn)*rs*g[c0+7]+b[c0+7];
    bf16x8 r;
    r[0]=(__bf16)q[0]; r[1]=(__bf16)q[1]; r[2]=(__bf16)q[2]; r[3]=(__bf16)q[3];
    r[4]=(__bf16)q[4]; r[5]=(__bf16)q[5]; r[6]=(__bf16)q[6]; r[7]=(__bf16)q[7];
    afr[k0] = r;
  }
}

// ------------- prep: swizzle Wt (timebias layout) + 10 GEMM weights ---------
// wf layout (bf16x8 units): [((mat*8 + nt)*4 + k0)*64 + lane], mat = blk*5 + {q,k,v,W1,W2}
__global__ void k_prep(const float* __restrict__ Wt,
                       const float* __restrict__ Wq, const float* __restrict__ Wk,
                       const float* __restrict__ Wv, const float* __restrict__ W1,
                       const float* __restrict__ W2,
                       unsigned short* __restrict__ bfg, unsigned short* __restrict__ wf){
  int idx = blockIdx.x * 256 + threadIdx.x;      // 196608 threads
  if (idx < 32768){
    int jj   = idx & 7;
    int lane = (idx >> 3) & 63;
    int k0   = (idx >> 9) & 3;
    int nt   = idx >> 11;
    int d    = k0 * 32 + (lane >> 4) * 8 + jj;
    int col  = (nt & 7) * 16 + (lane & 15);
    int blk  = nt >> 3;
    bfg[idx] = bfbits(Wt[blk * D * D + d * D + col]);
  } else {
    int i2 = idx - 32768;
    int jj = i2 & 7, lane = (i2 >> 3) & 63, k0 = (i2 >> 9) & 3, nt = (i2 >> 11) & 7;
    int mat = i2 >> 14;                          // 0..9
    int blk = mat / 5, m5 = mat % 5;
    const float* W = (m5 == 0 ? Wq : m5 == 1 ? Wk : m5 == 2 ? Wv : m5 == 3 ? W1 : W2)
                     + blk * D * D;
    int d = k0 * 32 + (lane >> 4) * 8 + jj;
    int col = nt * 16 + (lane & 15);
    wf[i2] = bfbits(W[d * D + col]);
  }
}

// ----- fused launch: causal timebias (blocks < NTB) + LN1/QKV block0 --------
// timebias: only (q,k) rows with k <= q are computed (causal mask kills k > q;
// pad-row weights are uniform and independent of logtw).
__global__ __launch_bounds__(256, 2) void k_tb_qkv(
    const float* __restrict__ T, const unsigned short* __restrict__ bfg,
    const float* __restrict__ bt, const float* __restrict__ wtp,
    const float* __restrict__ btp, float* __restrict__ logtw,
    const float* __restrict__ src, const int* __restrict__ ls,
    const float* __restrict__ g1, const float* __restrict__ b1,
    const unsigned short* __restrict__ wf,
    const float* __restrict__ bq, const float* __restrict__ bk,
    const float* __restrict__ bv,
    float* __restrict__ Q, unsigned short* __restrict__ qA,
    unsigned short* __restrict__ kB, unsigned short* __restrict__ vB){
  __shared__ __align__(16) unsigned short bsh[16384];   // 32 KB (timebias)
  __shared__ float bts[128], wtps[128];
  __shared__ float xs[16][XLD];                         // (qkv)
  __shared__ float mean_s[16], rstd_s[16];
  __shared__ float g1s[128], b1s[128];
  int tid = threadIdx.x;
  int lane = tid & 63, w = tid >> 6;
  int quad = lane >> 4;

  if (blockIdx.x < NTB){
    // ---------------- causal timebias ----------------
    int m = lane & 15;
    const bf16x8* bls = (const bf16x8*)bsh;
    // strip id -> (q, k_base): bands b=q>>6 have (b+1) strips per q
    int strip = blockIdx.x * 4 + w;              // 0..2303
    int b = 0;
#pragma unroll
    for (int i = 1; i < 8; ++i) if (strip >= 32 * i * (i + 1)) b = i;
    int r0 = strip - 32 * b * (b + 1);
    int q  = b * 64 + r0 / (b + 1);
    int kb = (r0 % (b + 1)) * 64;
    int wbase = q * L + kb;                      // flat row into T / logtw[blk]

    bf16x8 afr[4][4];
#pragma unroll
    for (int mt = 0; mt < 4; ++mt){
      const float* tp = T + (size_t)(wbase + mt * 16 + m) * D + quad * 8;
#pragma unroll
      for (int k0 = 0; k0 < 4; ++k0){
        float4 f0 = *(const float4*)(tp + k0 * 32);
        float4 f1 = *(const float4*)(tp + k0 * 32 + 4);
        afr[mt][k0] = cvt8(f0, f1);
      }
    }

#pragma unroll
    for (int blk = 0; blk < 2; ++blk){
      if (blk) __syncthreads();                 // protect bsh overwrite
      {
        const uint4* g = (const uint4*)(bfg + blk * 16384);
        uint4* s = (uint4*)bsh;
#pragma unroll
        for (int i = 0; i < 8; ++i) s[tid + i * 256] = g[tid + i * 256];
        if (tid < 128){ bts[tid] = bt[blk * 128 + tid]; wtps[tid] = wtp[blk * 128 + tid]; }
      }
      __syncthreads();

      f32x4 rs[4] = {{0,0,0,0},{0,0,0,0},{0,0,0,0},{0,0,0,0}};
#pragma unroll
      for (int ntl = 0; ntl < 8; ++ntl){
        f32x4 acc[4] = {{0,0,0,0},{0,0,0,0},{0,0,0,0},{0,0,0,0}};
#pragma unroll
        for (int k0 = 0; k0 < 4; ++k0){
          bf16x8 bfr = bls[(ntl * 4 + k0) * 64 + lane];
#pragma unroll
          for (int mt = 0; mt < 4; ++mt)
            acc[mt] = __builtin_amdgcn_mfma_f32_16x16x32_bf16(afr[mt][k0], bfr, acc[mt], 0, 0, 0);
        }
        float btv = bts[ntl * 16 + m];
        float wtv = wtps[ntl * 16 + m];
#pragma unroll
        for (int mt = 0; mt < 4; ++mt)
#pragma unroll
          for (int r = 0; r < 4; ++r)
            rs[mt][r] += fmaxf(acc[mt][r] + btv, 0.f) * wtv;
      }
#pragma unroll
      for (int mt = 0; mt < 4; ++mt)
#pragma unroll
        for (int r = 0; r < 4; ++r){
          float v = rs[mt][r];
          v += __shfl_xor(v, 1); v += __shfl_xor(v, 2);
          v += __shfl_xor(v, 4); v += __shfl_xor(v, 8);
          rs[mt][r] = v;
        }
      if (m == 0){
        float bp = btp[blk];
        float* out = logtw + blk * (L * L);
#pragma unroll
        for (int mt = 0; mt < 4; ++mt){
          float4 o;
          float s0 = rs[mt][0] + bp; o.x = -__logf(1.f + __expf(-s0));
          float s1 = rs[mt][1] + bp; o.y = -__logf(1.f + __expf(-s1));
          float s2 = rs[mt][2] + bp; o.z = -__logf(1.f + __expf(-s2));
          float s3 = rs[mt][3] + bp; o.w = -__logf(1.f + __expf(-s3));
          *(float4*)(out + wbase + mt * 16 + quad * 4) = o;
        }
      }
    }
    return;
  }

  // ---------------- LN1 + QKV for transformer block 0 ----------------
  int bi = blockIdx.x - NTB;                     // 0..95
  int rowbase = (bi & 31) * 16;
  int mat = bi >> 5;                             // 0=q,1=k,2=v
  int row_l = tid >> 4, seg = tid & 15;

  const float* sp = src + (rowbase + row_l) * D + seg * 8;
  float4 f0 = *(const float4*)sp, f1 = *(const float4*)(sp + 4);
  if (ls[rowbase + row_l] == 0){
    f0 = make_float4(0,0,0,0); f1 = make_float4(0,0,0,0);
  }
  *(float4*)&xs[row_l][seg * 8] = f0;
  *(float4*)&xs[row_l][seg * 8 + 4] = f1;
  if (mat == 0 && tid < 128){ g1s[tid] = g1[tid]; b1s[tid] = b1[tid]; }
  __syncthreads();
  if (mat == 0){
    row_stats16(xs, tid, mean_s, rstd_s);
    __syncthreads();
    float mn = mean_s[row_l], rs = rstd_s[row_l];
    float* qp = Q + (rowbase + row_l) * D + seg * 8;
    float4 o0, o1;
    int c0 = seg * 8;
    o0.x=(f0.x-mn)*rs*g1s[c0+0]+b1s[c0+0]; o0.y=(f0.y-mn)*rs*g1s[c0+1]+b1s[c0+1];
    o0.z=(f0.z-mn)*rs*g1s[c0+2]+b1s[c0+2]; o0.w=(f0.w-mn)*rs*g1s[c0+3]+b1s[c0+3];
    o1.x=(f1.x-mn)*rs*g1s[c0+4]+b1s[c0+4]; o1.y=(f1.y-mn)*rs*g1s[c0+5]+b1s[c0+5];
    o1.z=(f1.z-mn)*rs*g1s[c0+6]+b1s[c0+6]; o1.w=(f1.w-mn)*rs*g1s[c0+7]+b1s[c0+7];
    *(float4*)qp = o0; *(float4*)(qp + 4) = o1;
  }

  int mcol = lane & 15;
  bf16x8 afr[4];
  if (mat == 0) build_afr_ln(xs, lane, mean_s, rstd_s, g1s, b1s, afr);
  else          build_afr(xs, lane, afr);

  const float* bias_v = (mat == 0 ? bq : mat == 1 ? bk : bv);
#pragma unroll
  for (int jl = 0; jl < 2; ++jl){
    int nt = w * 2 + jl;
    const bf16x8* wfb = (const bf16x8*)wf + ((size_t)mat * 8 + nt) * 4 * 64;
    f32x4 acc = {0, 0, 0, 0};
#pragma unroll
    for (int k0 = 0; k0 < 4; ++k0)
      acc = __builtin_amdgcn_mfma_f32_16x16x32_bf16(afr[k0], wfb[k0 * 64 + lane], acc, 0, 0, 0);
    int c = nt * 16 + mcol;
    float bias = bias_v[c];
#pragma unroll
    for (int r = 0; r < 4; ++r){
      int row = rowbase + quad * 4 + r;
      float v = acc[r] + bias;
      if (mat == 0) write_qA(qA, row, c, v);
      else if (mat == 1) write_kB(kB, row, c, v);
      else write_vB(vB, row, c, v);
    }
  }
}

// ---------------- MFMA attention: block = (qtile of 16 rows, head) ----------
// Causal skip: wave chunks entirely above the diagonal skip score/PV MFMAs.
__global__ __launch_bounds__(256) void k_attn(
    const unsigned short* __restrict__ qA, const unsigned short* __restrict__ kB,
    const unsigned short* __restrict__ vB, const float* __restrict__ logtw,
    const int* __restrict__ ls, const float* __restrict__ Q,
    float* __restrict__ wout, float* __restrict__ xr){
  __shared__ __align__(16) unsigned short pa[16 * 64 * 8];
  __shared__ float pvp[4][2][64][4];
  __shared__ float smax[4][16], ssum[4][16];
  int qt = blockIdx.x >> 2, h = blockIdx.x & 3;
  int tid = threadIdx.x, lane = tid & 63, w = tid >> 6;
  int quad = lane >> 4, mcol = lane & 15;
  const float RS = 0.17677669529663687f;
  int row_max = qt * 16 + 15;
  bool skipw = (w * 128) > row_max;              // whole 128-col chunk masked

  float e[8][4];
  if (!skipw){
    bf16x8 qf = ((const bf16x8*)qA)[(qt * 4 + h) * 64 + lane];
    f32x4 acc[8];
#pragma unroll
    for (int nt8 = 0; nt8 < 8; ++nt8){
      bf16x8 bf = ((const bf16x8*)kB)[(h * 32 + w * 8 + nt8) * 64 + lane];
      f32x4 z = {0, 0, 0, 0};
      acc[nt8] = __builtin_amdgcn_mfma_f32_16x16x32_bf16(qf, bf, z, 0, 0, 0);
    }
#pragma unroll
    for (int nt8 = 0; nt8 < 8; ++nt8){
      int col = w * 128 + nt8 * 16 + mcol;
#pragma unroll
      for (int r = 0; r < 4; ++r){
        int row = qt * 16 + quad * 4 + r;
        float sv = (acc[nt8][r] + logtw[row * L + col]) * RS;
        e[nt8][r] = (col <= row) ? sv : -3e38f;
      }
    }
  } else {
#pragma unroll
    for (int nt8 = 0; nt8 < 8; ++nt8)
#pragma unroll
      for (int r = 0; r < 4; ++r) e[nt8][r] = -3e38f;
  }

  float mx4[4] = {-3e38f, -3e38f, -3e38f, -3e38f};
#pragma unroll
  for (int nt8 = 0; nt8 < 8; ++nt8)
#pragma unroll
    for (int r = 0; r < 4; ++r) mx4[r] = fmaxf(mx4[r], e[nt8][r]);
#pragma unroll
  for (int r = 0; r < 4; ++r){
    float v = mx4[r];
    v = fmaxf(v, __shfl_xor(v, 1)); v = fmaxf(v, __shfl_xor(v, 2));
    v = fmaxf(v, __shfl_xor(v, 4)); v = fmaxf(v, __shfl_xor(v, 8));
    mx4[r] = v;
  }
  if (mcol == 0){
#pragma unroll
    for (int r = 0; r < 4; ++r) smax[w][quad * 4 + r] = mx4[r];
  }
  __syncthreads();
  float mxr[4], sum4[4] = {0, 0, 0, 0};
#pragma unroll
  for (int r = 0; r < 4; ++r){
    int rr = quad * 4 + r;
    mxr[r] = fmaxf(fmaxf(smax[0][rr], smax[1][rr]), fmaxf(smax[2][rr], smax[3][rr]));
  }
#pragma unroll
  for (int nt8 = 0; nt8 < 8; ++nt8)
#pragma unroll
    for (int r = 0; r < 4; ++r){
      float sv = e[nt8][r];
      float ev = (sv > -1e38f) ? __expf(sv - mxr[r]) : 0.f;
      e[nt8][r] = ev;
      sum4[r] += ev;
    }
#pragma unroll
  for (int r = 0; r < 4; ++r){
    float v = sum4[r];
    v += __shfl_xor(v, 1); v += __shfl_xor(v, 2);
    v += __shfl_xor(v, 4); v += __shfl_xor(v, 8);
    sum4[r] = v;
  }
  if (mcol == 0){
#pragma unroll
    for (int r = 0; r < 4; ++r) ssum[w][quad * 4 + r] = sum4[r];
  }
  __syncthreads();
  float inv[4]; int padr[4];
#pragma unroll
  for (int r = 0; r < 4; ++r){
    int rr = quad * 4 + r;
    inv[r] = 1.f / (ssum[0][rr] + ssum[1][rr] + ssum[2][rr] + ssum[3][rr]);
    padr[r] = (ls[qt * 16 + rr] == 0);
  }
#pragma unroll
  for (int nt8 = 0; nt8 < 8; ++nt8){
    int col = w * 128 + nt8 * 16 + mcol;
    int kk = col >> 5, qk = (col >> 3) & 3, jj = col & 7;
#pragma unroll
    for (int r = 0; r < 4; ++r){
      int rl = quad * 4 + r;
      float wv = padr[r] ? (1.f / 512.f) : e[nt8][r] * inv[r];
      wout[h * (L * L) + (qt * 16 + rl) * L + col] = wv;
      if (!skipw) pa[(kk * 64 + qk * 16 + rl) * 8 + jj] = bfbits(wv);
    }
  }

  f32x4 pacc[2] = {{0,0,0,0},{0,0,0,0}};
  if (!skipw){
#pragma unroll
    for (int kk4 = 0; kk4 < 4; ++kk4){
      int kk = w * 4 + kk4;
      bf16x8 af = ((const bf16x8*)pa)[kk * 64 + lane];
#pragma unroll
      for (int nt = 0; nt < 2; ++nt){
        bf16x8 bf = ((const bf16x8*)vB)[((h * 16 + kk) * 2 + nt) * 64 + lane];
        pacc[nt] = __builtin_amdgcn_mfma_f32_16x16x32_bf16(af, bf, pacc[nt], 0, 0, 0);
      }
    }
  }
#pragma unroll
  for (int nt = 0; nt < 2; ++nt)
#pragma unroll
    for (int r = 0; r < 4; ++r) pvp[w][nt][lane][r] = pacc[nt][r];
  __syncthreads();
  if (w < 2){
    int nt = w;
#pragma unroll
    for (int r = 0; r < 4; ++r){
      float o = pvp[0][nt][lane][r] + pvp[1][nt][lane][r]
              + pvp[2][nt][lane][r] + pvp[3][nt][lane][r];
      int row = qt * 16 + quad * 4 + r;
      int cg = h * HD + nt * 16 + mcol;
      xr[row * D + cg] = Q[row * D + cg] + o;
    }
  }
}

// ---- MFMA LN2+FFN (+keep); optional fused LN1+QKV of next block / final LN --
__global__ __launch_bounds__(256) void k_ffn_m(
    const float* __restrict__ xr, const int* __restrict__ ls,
    const float* __restrict__ g2, const float* __restrict__ b2,
    const unsigned short* __restrict__ wf, int mat1,
    const float* __restrict__ b1f, const float* __restrict__ b2f,
    int fuse_qkv, const float* __restrict__ g1, const float* __restrict__ b1,
    int matq, const float* __restrict__ bq, const float* __restrict__ bk,
    const float* __restrict__ bv,
    float* __restrict__ Q, unsigned short* __restrict__ qA,
    unsigned short* __restrict__ kB, unsigned short* __restrict__ vB,
    int fuse_lnf, const float* __restrict__ lg, const float* __restrict__ lb,
    float* __restrict__ lf){
  __shared__ float xs[16][XLD];
  __shared__ float x2s[16][XLD];
  __shared__ float y1s[16][XLD];
  __shared__ float xos[16][XLD];
  __shared__ float mean_s[16], rstd_s[16];
  __shared__ float gs[128], bs[128];
  int tid = threadIdx.x, rowbase = blockIdx.x * 16;
  int row_l = tid >> 4, seg = tid & 15;
  int lane = tid & 63, w = tid >> 6;
  int quad = lane >> 4, mcol = lane & 15;

  {
    const float* sp = xr + (rowbase + row_l) * D + seg * 8;
    *(float4*)&xs[row_l][seg * 8] = *(const float4*)sp;
    *(float4*)&xs[row_l][seg * 8 + 4] = *(const float4*)(sp + 4);
    if (tid < 128){ gs[tid] = g2[tid]; bs[tid] = b2[tid]; }
  }
  __syncthreads();
  row_stats16(xs, tid, mean_s, rstd_s);
  __syncthreads();
  {
    float mn = mean_s[row_l], rs = rstd_s[row_l];
#pragma unroll
    for (int i = 0; i < 8; ++i){
      int c = seg * 8 + i;
      x2s[row_l][c] = (xs[row_l][c] - mn) * rs * gs[c] + bs[c];
    }
  }
  __syncthreads();

  bf16x8 afr[4];
  build_afr(x2s, lane, afr);
#pragma unroll
  for (int jl = 0; jl < 2; ++jl){
    int nt = w * 2 + jl;
    const bf16x8* wfb = (const bf16x8*)wf + ((size_t)mat1 * 8 + nt) * 4 * 64;
    f32x4 acc = {0, 0, 0, 0};
#pragma unroll
    for (int k0 = 0; k0 < 4; ++k0)
      acc = __builtin_amdgcn_mfma_f32_16x16x32_bf16(afr[k0], wfb[k0 * 64 + lane], acc, 0, 0, 0);
    int c = nt * 16 + mcol;
    float bias = b1f[c];
#pragma unroll
    for (int r = 0; r < 4; ++r)
      y1s[quad * 4 + r][c] = fmaxf(acc[r] + bias, 0.f);
  }
  __syncthreads();

  build_afr(y1s, lane, afr);
#pragma unroll
  for (int jl = 0; jl < 2; ++jl){
    int nt = w * 2 + jl;
    const bf16x8* wfb = (const bf16x8*)wf + ((size_t)(mat1 + 1) * 8 + nt) * 4 * 64;
    f32x4 acc = {0, 0, 0, 0};
#pragma unroll
    for (int k0 = 0; k0 < 4; ++k0)
      acc = __builtin_amdgcn_mfma_f32_16x16x32_bf16(afr[k0], wfb[k0 * 64 + lane], acc, 0, 0, 0);
    int c = nt * 16 + mcol;
    float bias = b2f[c];
#pragma unroll
    for (int r = 0; r < 4; ++r){
      int rl = quad * 4 + r;
      float kp = (ls[rowbase + rl] != 0) ? 1.f : 0.f;
      xos[rl][c] = (x2s[rl][c] + acc[r] + bias) * kp;   // residual adds post-LN2 x2
    }
  }
  __syncthreads();

  if (fuse_qkv){
    if (tid < 128){ gs[tid] = g1[tid]; bs[tid] = b1[tid]; }
    row_stats16(xos, tid, mean_s, rstd_s);
    __syncthreads();
    {
      float mn = mean_s[row_l], rs = rstd_s[row_l];
      float* qp = Q + (rowbase + row_l) * D + seg * 8;
      float4 o0, o1;
      int c0 = seg * 8;
      o0.x=(xos[row_l][c0+0]-mn)*rs*gs[c0+0]+bs[c0+0];
      o0.y=(xos[row_l][c0+1]-mn)*rs*gs[c0+1]+bs[c0+1];
      o0.z=(xos[row_l][c0+2]-mn)*rs*gs[c0+2]+bs[c0+2];
      o0.w=(xos[row_l][c0+3]-mn)*rs*gs[c0+3]+bs[c0+3];
      o1.x=(xos[row_l][c0+4]-mn)*rs*gs[c0+4]+bs[c0+4];
      o1.y=(xos[row_l][c0+5]-mn)*rs*gs[c0+5]+bs[c0+5];
      o1.z=(xos[row_l][c0+6]-mn)*rs*gs[c0+6]+bs[c0+6];
      o1.w=(xos[row_l][c0+7]-mn)*rs*gs[c0+7]+bs[c0+7];
      *(float4*)qp = o0; *(float4*)(qp + 4) = o1;
    }
    bf16x8 afrQ[4], afrX[4];
    build_afr_ln(xos, lane, mean_s, rstd_s, gs, bs, afrQ);
    build_afr(xos, lane, afrX);
#pragma unroll
    for (int jl = 0; jl < 6; ++jl){
      int j = w * 6 + jl;
      int mat = j >> 3, nt = j & 7;
      const bf16x8* wfb = (const bf16x8*)wf + ((size_t)(matq + mat) * 8 + nt) * 4 * 64;
      f32x4 acc = {0, 0, 0, 0};
#pragma unroll
      for (int k0 = 0; k0 < 4; ++k0)
        acc = __builtin_amdgcn_mfma_f32_16x16x32_bf16(mat == 0 ? afrQ[k0] : afrX[k0],
                                                      wfb[k0 * 64 + lane], acc, 0, 0, 0);
      int c = nt * 16 + mcol;
      float bias = (mat == 0 ? bq : mat == 1 ? bk : bv)[c];
#pragma unroll
      for (int r = 0; r < 4; ++r){
        int row = rowbase + quad * 4 + r;
        float v = acc[r] + bias;
        if (mat == 0) write_qA(qA, row, c, v);
        else if (mat == 1) write_kB(kB, row, c, v);
        else write_vB(vB, row, c, v);
      }
    }
  }

  if (fuse_lnf){
    if (tid < 128){ gs[tid] = lg[tid]; bs[tid] = lb[tid]; }
    row_stats16(xos, tid, mean_s, rstd_s);
    __syncthreads();
    float mn = mean_s[row_l], rs = rstd_s[row_l];
    float* op = lf + (rowbase + row_l) * D + seg * 8;
    float4 o0, o1;
    int c0 = seg * 8;
    o0.x=(xos[row_l][c0+0]-mn)*rs*gs[c0+0]+bs[c0+0];
    o0.y=(xos[row_l][c0+1]-mn)*rs*gs[c0+1]+bs[c0+1];
    o0.z=(xos[row_l][c0+2]-mn)*rs*gs[c0+2]+bs[c0+2];
    o0.w=(xos[row_l][c0+3]-mn)*rs*gs[c0+3]+bs[c0+3];
    o1.x=(xos[row_l][c0+4]-mn)*rs*gs[c0+4]+bs[c0+4];
    o1.y=(xos[row_l][c0+5]-mn)*rs*gs[c0+5]+bs[c0+5];
    o1.z=(xos[row_l][c0+6]-mn)*rs*gs[c0+6]+bs[c0+6];
    o1.w=(xos[row_l][c0+7]-mn)*rs*gs[c0+7]+bs[c0+7];
    *(float4*)op = o0; *(float4*)(op + 4) = o1;
  }
}

extern "C" void kernel_launch(void* const* d_in, const int* in_sizes, int n_in,
                              void* d_out, int out_size, void* d_ws, size_t ws_size,
                              hipStream_t stream){
  const int*   ls   = (const int*)d_in[0];
  const float* seqs = (const float*)d_in[1];
  const float* T    = (const float*)d_in[2];
  const float* Wq   = (const float*)d_in[3];
  const float* bq   = (const float*)d_in[4];
  const float* Wk   = (const float*)d_in[5];
  const float* bk   = (const float*)d_in[6];
  const float* Wv   = (const float*)d_in[7];
  const float* bv   = (const float*)d_in[8];
  const float* Wt   = (const float*)d_in[9];
  const float* bt   = (const float*)d_in[10];
  const float* Wtp  = (const float*)d_in[11];
  const float* btp  = (const float*)d_in[12];
  const float* g1   = (const float*)d_in[13];
  const float* b1   = (const float*)d_in[14];
  const float* g2   = (const float*)d_in[15];
  const float* b2   = (const float*)d_in[16];
  const float* W1   = (const float*)d_in[17];
  const float* b1f  = (const float*)d_in[18];
  const float* W2   = (const float*)d_in[19];
  const float* b2f  = (const float*)d_in[20];
  const float* lg   = (const float*)d_in[21];
  const float* lb   = (const float*)d_in[22];

  float* ws    = (float*)d_ws;
  float* Q     = ws;                  // 65536
  float* xr    = Q + 65536;           // 65536
  float* logtw = xr + 65536;          // 2*262144 (upper triangle left unwritten; never read)
  unsigned short* bfg = (unsigned short*)(logtw + 2 * 262144);  // 32768
  unsigned short* wf  = bfg + 32768;  // 163840
  unsigned short* qA  = wf + 163840;  // 65536
  unsigned short* kB  = qA + 65536;   // 65536
  unsigned short* vB  = kB + 65536;   // 65536

  float* outF = (float*)d_out;
  float* lf = outF;
  float* w0 = outF + 65536;
  float* w1 = w0 + 1048576;

  k_prep  <<<768, 256, 0, stream>>>(Wt, Wq, Wk, Wv, W1, W2, bfg, wf);
  // fused: causal timebias (576 blocks) + LN1/QKV block0 (96 blocks)
  k_tb_qkv<<<NTB + 96, 256, 0, stream>>>(T, bfg, bt, Wtp, btp, logtw,
                                         seqs, ls, g1, b1, wf, bq, bk, bv,
                                         Q, qA, kB, vB);
  // block 0
  k_attn<<<128, 256, 0, stream>>>(qA, kB, vB, logtw, ls, Q, w0, xr);
  k_ffn_m<<<32, 256, 0, stream>>>(xr, ls, g2, b2, wf, 3, b1f, b2f,
                                  1, g1 + D, b1 + D, 5, bq + D, bk + D, bv + D,
                                  Q, qA, kB, vB,
                                  0, lg, lb, lf);
  // block 1
  k_attn<<<128, 256, 0, stream>>>(qA, kB, vB, logtw + L * L, ls, Q, w1, xr);
  k_ffn_m<<<32, 256, 0, stream>>>(xr, ls, g2 + D, b2 + D, wf, 8, b1f + D, b2f + D,
                                  0, g1, b1, 0, bq, bk, bv,
                                  Q, qA, kB, vB,
                                  1, lg, lb, lf);
}